// Round 1
// baseline (1632.870 us; speedup 1.0000x reference)
//
#include <hip/hip_runtime.h>
#include <cstdint>
#include <cstddef>

#define B_ 8
#define S_ 1024
#define D_ 512
#define H_ 8
#define DH_ 64
#define DFF_ 2048
#define STEPS_ 6
#define M_ (B_*S_)   // 8192 tokens

typedef unsigned short u16;
typedef u16   u16x8 __attribute__((ext_vector_type(8)));
typedef short s16x8 __attribute__((ext_vector_type(8)));
typedef float f32x4 __attribute__((ext_vector_type(4)));

__device__ __forceinline__ u16 f2b(float f){
  union { float f; unsigned u; } v; v.f = f;
  unsigned r = v.u + 0x7fffu + ((v.u >> 16) & 1u);
  return (u16)(r >> 16);
}
__device__ __forceinline__ float b2f(u16 u){
  union { unsigned u; float f; } v; v.u = ((unsigned)u) << 16;
  return v.f;
}
__device__ __forceinline__ void gload16(const void* g, void* l){
  __builtin_amdgcn_global_load_lds(
    (const __attribute__((address_space(1))) void*)g,
    (__attribute__((address_space(3))) void*)l, 16, 0, 0);
}
__device__ __forceinline__ float wred_sum(float v){
  #pragma unroll
  for (int m = 1; m < 64; m <<= 1) v += __shfl_xor(v, m, 64);
  return v;
}

// ---------------- prep: st = x (f32), stb = bf16(x) ----------------
__global__ __launch_bounds__(256) void prep_kernel(const float* __restrict__ x,
    float* __restrict__ st, u16* __restrict__ stb){
  size_t i = (size_t)blockIdx.x*256 + threadIdx.x;     // group of 8 elems
  const float4* xp = (const float4*)x + i*2;
  float4 a = xp[0], b = xp[1];
  ((float4*)st)[i*2]   = a;
  ((float4*)st)[i*2+1] = b;
  u16x8 o;
  o[0]=f2b(a.x); o[1]=f2b(a.y); o[2]=f2b(a.z); o[3]=f2b(a.w);
  o[4]=f2b(b.x); o[5]=f2b(b.y); o[6]=f2b(b.z); o[7]=f2b(b.w);
  ((u16x8*)stb)[i] = o;
}

__global__ void zero_kernel(float* __restrict__ p){
  p[(size_t)blockIdx.x*256 + threadIdx.x] = 0.f;
}

// W [K][N] f32 -> Wt [N][K] bf16
__global__ void tcast_kernel(const float* __restrict__ W, u16* __restrict__ Wt,
                             int K, int N){
  int i = blockIdx.x*256 + threadIdx.x;
  if (i >= N*K) return;
  int n = i / K, k = i - n*K;
  Wt[i] = f2b(W[(size_t)k*N + n]);
}

__global__ void packb_kernel(const float* __restrict__ bq, const float* __restrict__ bk,
                             const float* __restrict__ bv, float* __restrict__ bqkv){
  int i = blockIdx.x*256 + threadIdx.x;
  if (i < 512)       bqkv[i] = bq[i];
  else if (i < 1024) bqkv[i] = bk[i-512];
  else if (i < 1536) bqkv[i] = bv[i-1024];
}

// ---------------- GEMM: C = A[M][K](bf16) * Bt[N][K](bf16)^T + bias ----------------
// EPI: 0 = f32 out, 1 = bf16 out, 2 = bf16 relu out
template<int EPI>
__global__ __launch_bounds__(256) void gemm_kernel(
    const u16* __restrict__ A, const u16* __restrict__ Bt,
    const float* __restrict__ bias, void* __restrict__ C,
    int ntn, int K, int ldo){
  __shared__ u16 As[128*32];
  __shared__ u16 Bs[128*32];
  int tid = threadIdx.x; int lane = tid & 63; int w = tid >> 6;
  int wm = w >> 1, wn = w & 1;
  int tn = blockIdx.x % ntn, tm = blockIdx.x / ntn;
  int m0 = tm*128, n0 = tn*128;
  size_t aoff = (size_t)(m0 + w*32 + (lane>>2))*K + ((lane&3)*8);
  size_t boff = (size_t)(n0 + w*32 + (lane>>2))*K + ((lane&3)*8);
  f32x4 acc[4][4];
  #pragma unroll
  for (int i=0;i<4;i++)
    #pragma unroll
    for (int j=0;j<4;j++) acc[i][j] = (f32x4){0.f,0.f,0.f,0.f};

  for (int k0 = 0; k0 < K; k0 += 32){
    gload16(A  + aoff + k0,                 &As[w*1024]);
    gload16(A  + aoff + (size_t)16*K + k0,  &As[w*1024 + 512]);
    gload16(Bt + boff + k0,                 &Bs[w*1024]);
    gload16(Bt + boff + (size_t)16*K + k0,  &Bs[w*1024 + 512]);
    __syncthreads();
    s16x8 af[4], bf[4];
    #pragma unroll
    for (int mi=0;mi<4;mi++)
      af[mi] = *(const s16x8*)&As[(wm*64 + mi*16 + (lane&15))*32 + ((lane>>4)*8)];
    #pragma unroll
    for (int ni=0;ni<4;ni++)
      bf[ni] = *(const s16x8*)&Bs[(wn*64 + ni*16 + (lane&15))*32 + ((lane>>4)*8)];
    #pragma unroll
    for (int mi=0;mi<4;mi++)
      #pragma unroll
      for (int ni=0;ni<4;ni++)
        acc[mi][ni] = __builtin_amdgcn_mfma_f32_16x16x32_bf16(af[mi], bf[ni], acc[mi][ni], 0,0,0);
    __syncthreads();
  }

  #pragma unroll
  for (int mi=0;mi<4;mi++){
    int row0 = m0 + wm*64 + mi*16 + ((lane>>4)*4);
    #pragma unroll
    for (int ni=0;ni<4;ni++){
      int col = n0 + wn*64 + ni*16 + (lane&15);
      float bc = bias[col];
      #pragma unroll
      for (int r=0;r<4;r++){
        float v = acc[mi][ni][r] + bc;
        if (EPI == 2) v = fmaxf(v, 0.f);
        if (EPI == 0) ((float*)C)[(size_t)(row0+r)*ldo + col] = v;
        else          ((u16*) C)[(size_t)(row0+r)*ldo + col] = f2b(v);
      }
    }
  }
}

// ---------------- flash attention: qkv[M][1536] bf16 -> ctx[M][512] bf16 ----------------
__global__ __launch_bounds__(256) void attn_kernel(const u16* __restrict__ qkv,
                                                   u16* __restrict__ ctx){
  __shared__ u16 Ks[64*64];
  __shared__ u16 Vt[64*64];          // transposed: Vt[d][krow]
  __shared__ u16 Ps[4][16*64];       // per-wave P tile [16 qrows][64 krows]
  int tid = threadIdx.x, lane = tid & 63, w = tid >> 6;
  int bid = blockIdx.x;
  int qt = bid & 15, h = (bid >> 4) & 7, b = bid >> 7;
  size_t rowbase = (size_t)b * S_;

  // Q fragments (held in registers for whole kernel)
  int qrow = qt*64 + w*16 + (lane & 15);
  s16x8 aq[2];
  #pragma unroll
  for (int s=0;s<2;s++)
    aq[s] = *(const s16x8*)&qkv[(rowbase + qrow)*1536 + h*64 + s*32 + ((lane>>4)*8)];

  f32x4 o[4];
  #pragma unroll
  for (int i=0;i<4;i++) o[i] = (f32x4){0.f,0.f,0.f,0.f};
  float m_[4] = {-1e30f,-1e30f,-1e30f,-1e30f};
  float l_[4] = {0.f,0.f,0.f,0.f};

  for (int kt = 0; kt < 16; kt++){
    __syncthreads();   // previous iteration's reads done before overwrite
    // stage K tile and transposed V tile
    #pragma unroll
    for (int r2=0;r2<2;r2++){
      int e  = (r2*256 + tid)*8;
      int kr = e >> 6, c0 = e & 63;
      u16x8 k8 = *(const u16x8*)&qkv[(rowbase + kt*64 + kr)*1536 +  512 + h*64 + c0];
      *(u16x8*)&Ks[kr*64 + c0] = k8;
      u16x8 v8 = *(const u16x8*)&qkv[(rowbase + kt*64 + kr)*1536 + 1024 + h*64 + c0];
      #pragma unroll
      for (int j=0;j<8;j++) Vt[(c0+j)*64 + kr] = v8[j];
    }
    __syncthreads();

    // S = Q K^T * 0.125
    f32x4 sacc[4];
    #pragma unroll
    for (int nf=0;nf<4;nf++){
      f32x4 acc = (f32x4){0.f,0.f,0.f,0.f};
      #pragma unroll
      for (int s=0;s<2;s++){
        s16x8 bk = *(const s16x8*)&Ks[(nf*16 + (lane&15))*64 + s*32 + ((lane>>4)*8)];
        acc = __builtin_amdgcn_mfma_f32_16x16x32_bf16(aq[s], bk, acc, 0,0,0);
      }
      sacc[nf] = acc * 0.125f;
    }

    // online softmax per q-row (row = (lane>>4)*4 + r)
    #pragma unroll
    for (int r=0;r<4;r++){
      float mx = fmaxf(fmaxf(sacc[0][r], sacc[1][r]), fmaxf(sacc[2][r], sacc[3][r]));
      #pragma unroll
      for (int msk=1; msk<16; msk<<=1) mx = fmaxf(mx, __shfl_xor(mx, msk, 64));
      float mnew  = fmaxf(m_[r], mx);
      float alpha = __expf(m_[r] - mnew);
      float p0 = __expf(sacc[0][r]-mnew), p1 = __expf(sacc[1][r]-mnew);
      float p2 = __expf(sacc[2][r]-mnew), p3 = __expf(sacc[3][r]-mnew);
      float rs = p0+p1+p2+p3;
      #pragma unroll
      for (int msk=1; msk<16; msk<<=1) rs += __shfl_xor(rs, msk, 64);
      l_[r] = l_[r]*alpha + rs;
      m_[r] = mnew;
      #pragma unroll
      for (int df=0;df<4;df++) o[df][r] *= alpha;
      int prow = ((lane>>4)*4 + r);
      Ps[w][prow*64 +  0 + (lane&15)] = f2b(p0);
      Ps[w][prow*64 + 16 + (lane&15)] = f2b(p1);
      Ps[w][prow*64 + 32 + (lane&15)] = f2b(p2);
      Ps[w][prow*64 + 48 + (lane&15)] = f2b(p3);
    }
    // ensure same-wave P writes complete before A-layout re-read
    asm volatile("s_waitcnt lgkmcnt(0)" ::: "memory");

    // O += P V
    #pragma unroll
    for (int ks=0; ks<2; ks++){
      s16x8 ap = *(const s16x8*)&Ps[w][(lane&15)*64 + ks*32 + ((lane>>4)*8)];
      #pragma unroll
      for (int df=0;df<4;df++){
        s16x8 bv = *(const s16x8*)&Vt[(df*16 + (lane&15))*64 + ks*32 + ((lane>>4)*8)];
        o[df] = __builtin_amdgcn_mfma_f32_16x16x32_bf16(ap, bv, o[df], 0,0,0);
      }
    }
  }

  // write ctx (bf16)
  #pragma unroll
  for (int df=0;df<4;df++)
    #pragma unroll
    for (int r=0;r<4;r++){
      float v = o[df][r] / l_[r];
      size_t row = rowbase + qt*64 + w*16 + ((lane>>4)*4 + r);
      ctx[row*512 + h*64 + df*16 + (lane&15)] = f2b(v);
    }
}

// ---------------- LN1: out1 = LN(st + tmp), also bf16 copy ----------------
__global__ __launch_bounds__(64) void ln1_kernel(
    const float* __restrict__ tmp, const float* __restrict__ st,
    const float* __restrict__ g, const float* __restrict__ bt,
    float* __restrict__ out1, u16* __restrict__ out1b){
  int row = blockIdx.x, lane = threadIdx.x;
  size_t base = (size_t)row*512 + lane*8;
  float v[8];
  {
    const float4* tp = (const float4*)(tmp + base);
    const float4* sp = (const float4*)(st + base);
    float4 t0=tp[0], t1=tp[1], s0=sp[0], s1=sp[1];
    v[0]=t0.x+s0.x; v[1]=t0.y+s0.y; v[2]=t0.z+s0.z; v[3]=t0.w+s0.w;
    v[4]=t1.x+s1.x; v[5]=t1.y+s1.y; v[6]=t1.z+s1.z; v[7]=t1.w+s1.w;
  }
  float sum=0.f, sq=0.f;
  #pragma unroll
  for (int j=0;j<8;j++){ sum += v[j]; sq += v[j]*v[j]; }
  sum = wred_sum(sum); sq = wred_sum(sq);
  float mean = sum*(1.f/512.f);
  float var  = sq*(1.f/512.f) - mean*mean;
  float rstd = rsqrtf(fmaxf(var, 0.f) + 1e-6f);
  int c0 = lane*8;
  float y[8]; u16x8 ob;
  #pragma unroll
  for (int j=0;j<8;j++){ y[j] = (v[j]-mean)*rstd*g[c0+j] + bt[c0+j]; ob[j]=f2b(y[j]); }
  float4* op = (float4*)(out1 + base);
  op[0] = make_float4(y[0],y[1],y[2],y[3]);
  op[1] = make_float4(y[4],y[5],y[6],y[7]);
  *(u16x8*)(out1b + base) = ob;
}

// ---------------- LNf: in-place LN over DFF=2048 (relu already applied) ----------------
__global__ __launch_bounds__(256) void lnf_kernel(
    u16* __restrict__ hbuf, const float* __restrict__ g, const float* __restrict__ bt){
  int row = blockIdx.x, tid = threadIdx.x, lane = tid & 63, wv = tid >> 6;
  size_t base = (size_t)row*2048 + tid*8;
  u16x8 x8 = *(const u16x8*)&hbuf[base];
  float v[8];
  #pragma unroll
  for (int j=0;j<8;j++) v[j] = b2f(x8[j]);
  float sum=0.f, sq=0.f;
  #pragma unroll
  for (int j=0;j<8;j++){ sum += v[j]; sq += v[j]*v[j]; }
  sum = wred_sum(sum); sq = wred_sum(sq);
  __shared__ float rs[8];
  if (lane == 0){ rs[wv] = sum; rs[4+wv] = sq; }
  __syncthreads();
  sum = rs[0]+rs[1]+rs[2]+rs[3];
  sq  = rs[4]+rs[5]+rs[6]+rs[7];
  float mean = sum*(1.f/2048.f);
  float var  = sq*(1.f/2048.f) - mean*mean;
  float rstd = rsqrtf(fmaxf(var, 0.f) + 1e-6f);
  int c0 = tid*8;
  u16x8 o;
  #pragma unroll
  for (int j=0;j<8;j++) o[j] = f2b((v[j]-mean)*rstd*g[c0+j] + bt[c0+j]);
  *(u16x8*)&hbuf[base] = o;
}

// ---------------- LN2 + ACT mix: st = LN(out1+tmp)*uw + st*(1-uw) ----------------
__global__ __launch_bounds__(64) void ln2mix_kernel(
    const float* __restrict__ tmp, const float* __restrict__ out1,
    const float* __restrict__ g, const float* __restrict__ bt,
    const float* __restrict__ uw, float* __restrict__ st, u16* __restrict__ stb){
  int row = blockIdx.x, lane = threadIdx.x;
  size_t base = (size_t)row*512 + lane*8;
  float v[8], sv[8];
  {
    const float4* tp = (const float4*)(tmp  + base);
    const float4* op = (const float4*)(out1 + base);
    const float4* sp = (const float4*)(st   + base);
    float4 t0=tp[0], t1=tp[1], o0=op[0], o1=op[1], s0=sp[0], s1=sp[1];
    v[0]=t0.x+o0.x; v[1]=t0.y+o0.y; v[2]=t0.z+o0.z; v[3]=t0.w+o0.w;
    v[4]=t1.x+o1.x; v[5]=t1.y+o1.y; v[6]=t1.z+o1.z; v[7]=t1.w+o1.w;
    sv[0]=s0.x; sv[1]=s0.y; sv[2]=s0.z; sv[3]=s0.w;
    sv[4]=s1.x; sv[5]=s1.y; sv[6]=s1.z; sv[7]=s1.w;
  }
  float sum=0.f, sq=0.f;
  #pragma unroll
  for (int j=0;j<8;j++){ sum += v[j]; sq += v[j]*v[j]; }
  sum = wred_sum(sum); sq = wred_sum(sq);
  float mean = sum*(1.f/512.f);
  float var  = sq*(1.f/512.f) - mean*mean;
  float rstd = rsqrtf(fmaxf(var, 0.f) + 1e-6f);
  float u = uw[row], um1 = 1.f - u;
  int c0 = lane*8;
  float z[8]; u16x8 ob;
  #pragma unroll
  for (int j=0;j<8;j++){
    float y = (v[j]-mean)*rstd*g[c0+j] + bt[c0+j];
    z[j] = y*u + sv[j]*um1;
    ob[j] = f2b(z[j]);
  }
  float4* op = (float4*)(st + base);
  op[0] = make_float4(z[0],z[1],z[2],z[3]);
  op[1] = make_float4(z[4],z[5],z[6],z[7]);
  *(u16x8*)(stb + base) = ob;
}

// ---------------- ACT halting: p = sigmoid(st . act_w + act_b) ----------------
__global__ __launch_bounds__(256) void act_kernel(
    const float* __restrict__ st, const float* __restrict__ aw,
    const float* __restrict__ ab, float* __restrict__ hp,
    float* __restrict__ rem, float* __restrict__ uw){
  int lane = threadIdx.x & 63, wv = threadIdx.x >> 6;
  int tok = blockIdx.x*4 + wv;
  const float4* sp = (const float4*)(st + (size_t)tok*512) + lane*2;
  const float4* wp = (const float4*)aw + lane*2;
  float4 a0=sp[0], a1=sp[1], w0=wp[0], w1=wp[1];
  float d = a0.x*w0.x + a0.y*w0.y + a0.z*w0.z + a0.w*w0.w
          + a1.x*w1.x + a1.y*w1.y + a1.z*w1.z + a1.w*w1.w;
  d = wred_sum(d);
  if (lane == 0){
    float t = d + ab[0];
    float p = 1.f / (1.f + expf(-t));
    float h = hp[tok], r = rem[tok];
    float still = (h < 1.f) ? 1.f : 0.f;
    float cand  = h + p*still;
    float nh  = (cand > 0.99f)  ? still : 0.f;
    float st2 = (cand <= 0.99f) ? still : 0.f;
    h += p*st2;
    r += nh*(1.f - h);
    h += nh*r;
    hp[tok] = h; rem[tok] = r;
    uw[tok] = p*st2 + nh*r;
  }
}

// ---------------- host launch ----------------
extern "C" void kernel_launch(void* const* d_in, const int* in_sizes, int n_in,
                              void* d_out, int out_size, void* d_ws, size_t ws_size,
                              hipStream_t stream){
  const float* x     = (const float*)d_in[0];
  const float* wq    = (const float*)d_in[1];
  const float* bq    = (const float*)d_in[2];
  const float* wk    = (const float*)d_in[3];
  const float* bk    = (const float*)d_in[4];
  const float* wv    = (const float*)d_in[5];
  const float* bv    = (const float*)d_in[6];
  const float* wo    = (const float*)d_in[7];
  const float* bo    = (const float*)d_in[8];
  const float* w1    = (const float*)d_in[9];
  const float* b1    = (const float*)d_in[10];
  const float* lnf_g = (const float*)d_in[11];
  const float* lnf_b = (const float*)d_in[12];
  const float* w2    = (const float*)d_in[13];
  const float* b2    = (const float*)d_in[14];
  const float* ln1_g = (const float*)d_in[15];
  const float* ln1_b = (const float*)d_in[16];
  const float* ln2_g = (const float*)d_in[17];
  const float* ln2_b = (const float*)d_in[18];
  const float* aw    = (const float*)d_in[19];
  const float* ab    = (const float*)d_in[20];
  float* st = (float*)d_out;

  char* cur = (char*)d_ws;
  auto alloc = [&](size_t n){ void* p = cur; cur += (n + 255) & ~(size_t)255; return p; };
  u16*  wqkv_t = (u16*)alloc((size_t)1536*512*2);
  u16*  wo_t   = (u16*)alloc((size_t)512*512*2);
  u16*  w1_t   = (u16*)alloc((size_t)2048*512*2);
  u16*  w2_t   = (u16*)alloc((size_t)512*2048*2);
  float* bqkv  = (float*)alloc(1536*4);
  u16*  stb    = (u16*)alloc((size_t)M_*512*2);
  u16*  qkv    = (u16*)alloc((size_t)M_*1536*2);
  u16*  ctx    = (u16*)alloc((size_t)M_*512*2);
  u16*  out1b  = (u16*)alloc((size_t)M_*512*2);
  u16*  hbuf   = (u16*)alloc((size_t)M_*2048*2);
  float* tmp   = (float*)alloc((size_t)M_*512*4);
  float* out1  = (float*)alloc((size_t)M_*512*4);
  float* halt  = (float*)alloc((size_t)3*M_*4);
  float* hp = halt, *rem = halt + M_, *uw = halt + 2*M_;

  prep_kernel<<<2048, 256, 0, stream>>>(x, st, stb);
  zero_kernel<<<96, 256, 0, stream>>>(halt);
  packb_kernel<<<6, 256, 0, stream>>>(bq, bk, bv, bqkv);
  tcast_kernel<<<1024, 256, 0, stream>>>(wq, wqkv_t,            512, 512);
  tcast_kernel<<<1024, 256, 0, stream>>>(wk, wqkv_t + 512*512,  512, 512);
  tcast_kernel<<<1024, 256, 0, stream>>>(wv, wqkv_t + 1024*512, 512, 512);
  tcast_kernel<<<1024, 256, 0, stream>>>(wo, wo_t, 512, 512);
  tcast_kernel<<<4096, 256, 0, stream>>>(w1, w1_t, 512, 2048);
  tcast_kernel<<<4096, 256, 0, stream>>>(w2, w2_t, 2048, 512);

  for (int s = 0; s < STEPS_; s++){
    act_kernel<<<M_/4, 256, 0, stream>>>(st, aw, ab, hp, rem, uw);
    gemm_kernel<1><<<64*12, 256, 0, stream>>>(stb,   wqkv_t, bqkv, qkv,  12, 512,  1536);
    attn_kernel<<<1024, 256, 0, stream>>>(qkv, ctx);
    gemm_kernel<0><<<64*4,  256, 0, stream>>>(ctx,   wo_t,   bo,   tmp,  4,  512,  512);
    ln1_kernel<<<M_, 64, 0, stream>>>(tmp, st, ln1_g, ln1_b, out1, out1b);
    gemm_kernel<2><<<64*16, 256, 0, stream>>>(out1b, w1_t,   b1,   hbuf, 16, 512,  2048);
    lnf_kernel<<<M_, 256, 0, stream>>>(hbuf, lnf_g, lnf_b);
    gemm_kernel<0><<<64*4,  256, 0, stream>>>(hbuf,  w2_t,   b2,   tmp,  4,  2048, 512);
    ln2mix_kernel<<<M_, 64, 0, stream>>>(tmp, out1, ln2_g, ln2_b, uw, st, stb);
  }
}

// Round 2
// 1356.675 us; speedup vs baseline: 1.2036x; 1.2036x over previous
//
#include <hip/hip_runtime.h>
#include <cstdint>
#include <cstddef>

#define B_ 8
#define S_ 1024
#define D_ 512
#define H_ 8
#define DH_ 64
#define DFF_ 2048
#define STEPS_ 6
#define M_ (B_*S_)   // 8192 tokens

typedef unsigned short u16;
typedef u16   u16x8 __attribute__((ext_vector_type(8)));
typedef short s16x8 __attribute__((ext_vector_type(8)));
typedef float f32x4 __attribute__((ext_vector_type(4)));

__device__ __forceinline__ u16 f2b(float f){
  union { float f; unsigned u; } v; v.f = f;
  unsigned r = v.u + 0x7fffu + ((v.u >> 16) & 1u);
  return (u16)(r >> 16);
}
__device__ __forceinline__ float b2f(u16 u){
  union { unsigned u; float f; } v; v.u = ((unsigned)u) << 16;
  return v.f;
}
__device__ __forceinline__ void gload16(const void* g, void* l){
  __builtin_amdgcn_global_load_lds(
    (const __attribute__((address_space(1))) void*)g,
    (__attribute__((address_space(3))) void*)l, 16, 0, 0);
}
__device__ __forceinline__ float wred_sum(float v){
  #pragma unroll
  for (int m = 1; m < 64; m <<= 1) v += __shfl_xor(v, m, 64);
  return v;
}

// ---------------- prep: st = x, stb = bf16(x), dotb[row] = x_row . act_w ----------------
__global__ __launch_bounds__(256) void prep_kernel(const float* __restrict__ x,
    const float* __restrict__ aw, float* __restrict__ st, u16* __restrict__ stb,
    float* __restrict__ dotb){
  int tid = threadIdx.x; int l = tid & 63; int w = tid >> 6;
  size_t i = (size_t)blockIdx.x*256 + tid;     // group of 8 elems; one wave = one row
  const float4* xp = (const float4*)x + i*2;
  float4 a = xp[0], b = xp[1];
  ((float4*)st)[i*2]   = a;
  ((float4*)st)[i*2+1] = b;
  u16x8 o;
  o[0]=f2b(a.x); o[1]=f2b(a.y); o[2]=f2b(a.z); o[3]=f2b(a.w);
  o[4]=f2b(b.x); o[5]=f2b(b.y); o[6]=f2b(b.z); o[7]=f2b(b.w);
  ((u16x8*)stb)[i] = o;
  const float4* wp = (const float4*)aw + (size_t)l*2;
  float4 w0 = wp[0], w1 = wp[1];
  float d = a.x*w0.x + a.y*w0.y + a.z*w0.z + a.w*w0.w
          + b.x*w1.x + b.y*w1.y + b.z*w1.z + b.w*w1.w;
  d = wred_sum(d);
  if (l == 0) dotb[blockIdx.x*4 + w] = d;
}

__global__ void zero_kernel(float* __restrict__ p){
  p[(size_t)blockIdx.x*256 + threadIdx.x] = 0.f;
}

// ---------------- tiled transpose-cast: W[K][N] f32 -> Wt[N][K] bf16 ----------------
__global__ __launch_bounds__(256) void tcast_kernel(const float* __restrict__ W,
    u16* __restrict__ Wt, int K, int N){
  __shared__ u16 T[64*66];
  int tid = threadIdx.x;
  int nbt = N >> 6;
  int k0 = (blockIdx.x / nbt) << 6, n0 = (blockIdx.x % nbt) << 6;
  int r = tid >> 2, c4 = tid & 3;
  const float* src = W + (size_t)(k0 + r)*N + n0 + c4*16;
  #pragma unroll
  for (int q = 0; q < 2; q++){
    float4 f0 = ((const float4*)src)[q*2], f1 = ((const float4*)src)[q*2+1];
    u16x8 t;
    t[0]=f2b(f0.x); t[1]=f2b(f0.y); t[2]=f2b(f0.z); t[3]=f2b(f0.w);
    t[4]=f2b(f1.x); t[5]=f2b(f1.y); t[6]=f2b(f1.z); t[7]=f2b(f1.w);
    *(u16x8*)&T[r*66 + c4*16 + q*8] = t;
  }
  __syncthreads();
  int n = tid >> 2;
  #pragma unroll
  for (int t2 = 0; t2 < 2; t2++){
    int sc = (tid & 3) + t2*4;
    u16x8 o;
    #pragma unroll
    for (int j = 0; j < 8; j++) o[j] = T[(sc*8 + j)*66 + n];
    *(u16x8*)&Wt[(size_t)(n0 + n)*K + k0 + sc*8] = o;
  }
}

__global__ void packb_kernel(const float* __restrict__ bq, const float* __restrict__ bk,
                             const float* __restrict__ bv, float* __restrict__ bqkv){
  int i = blockIdx.x*256 + threadIdx.x;
  if (i < 512)       bqkv[i] = bq[i];
  else if (i < 1024) bqkv[i] = bk[i-512];
  else if (i < 1536) bqkv[i] = bv[i-1024];
}

// ---------------- GEMM: C = A[M][K](bf16) * Bt[N][K](bf16)^T + bias ----------------
// EPI: 0 = f32 out, 1 = bf16 out, 2 = bf16 relu out
template<int EPI>
__global__ __launch_bounds__(256) void gemm_kernel(
    const u16* __restrict__ A, const u16* __restrict__ Bt,
    const float* __restrict__ bias, void* __restrict__ C,
    int ntn, int K, int ldo){
  __shared__ u16 As[128*32];
  __shared__ u16 Bs[128*32];
  int tid = threadIdx.x; int lane = tid & 63; int w = tid >> 6;
  int wm = w >> 1, wn = w & 1;
  int tn = blockIdx.x % ntn, tm = blockIdx.x / ntn;
  int m0 = tm*128, n0 = tn*128;
  size_t aoff = (size_t)(m0 + w*32 + (lane>>2))*K + ((lane&3)*8);
  size_t boff = (size_t)(n0 + w*32 + (lane>>2))*K + ((lane&3)*8);
  f32x4 acc[4][4];
  #pragma unroll
  for (int i=0;i<4;i++)
    #pragma unroll
    for (int j=0;j<4;j++) acc[i][j] = (f32x4){0.f,0.f,0.f,0.f};

  for (int k0 = 0; k0 < K; k0 += 32){
    gload16(A  + aoff + k0,                 &As[w*1024]);
    gload16(A  + aoff + (size_t)16*K + k0,  &As[w*1024 + 512]);
    gload16(Bt + boff + k0,                 &Bs[w*1024]);
    gload16(Bt + boff + (size_t)16*K + k0,  &Bs[w*1024 + 512]);
    __syncthreads();
    s16x8 af[4], bf[4];
    #pragma unroll
    for (int mi=0;mi<4;mi++)
      af[mi] = *(const s16x8*)&As[(wm*64 + mi*16 + (lane&15))*32 + ((lane>>4)*8)];
    #pragma unroll
    for (int ni=0;ni<4;ni++)
      bf[ni] = *(const s16x8*)&Bs[(wn*64 + ni*16 + (lane&15))*32 + ((lane>>4)*8)];
    #pragma unroll
    for (int mi=0;mi<4;mi++)
      #pragma unroll
      for (int ni=0;ni<4;ni++)
        acc[mi][ni] = __builtin_amdgcn_mfma_f32_16x16x32_bf16(af[mi], bf[ni], acc[mi][ni], 0,0,0);
    __syncthreads();
  }

  #pragma unroll
  for (int mi=0;mi<4;mi++){
    int row0 = m0 + wm*64 + mi*16 + ((lane>>4)*4);
    #pragma unroll
    for (int ni=0;ni<4;ni++){
      int col = n0 + wn*64 + ni*16 + (lane&15);
      float bc = bias[col];
      #pragma unroll
      for (int r=0;r<4;r++){
        float v = acc[mi][ni][r] + bc;
        if (EPI == 2) v = fmaxf(v, 0.f);
        if (EPI == 0) ((float*)C)[(size_t)(row0+r)*ldo + col] = v;
        else          ((u16*) C)[(size_t)(row0+r)*ldo + col] = f2b(v);
      }
    }
  }
}

// ---------------- vtrans: qkv V-part [M][1536] -> vt[(b*8+h)*64+d][1024] ----------------
__global__ __launch_bounds__(256) void vtrans_kernel(const u16* __restrict__ qkv,
                                                     u16* __restrict__ vt){
  __shared__ u16 T[64*66];
  int tid = threadIdx.x;
  int bid = blockIdx.x;
  int st_ = bid & 15, h = (bid >> 4) & 7, b = bid >> 7;
  int s = tid >> 2, c4 = tid & 3;
  const u16* src = qkv + ((size_t)(b*1024 + st_*64 + s)*1536 + 1024 + h*64);
  *(u16x8*)&T[s*66 + c4*8]        = *(const u16x8*)(src + c4*8);
  *(u16x8*)&T[s*66 + (c4+4)*8]    = *(const u16x8*)(src + (c4+4)*8);
  __syncthreads();
  int d = tid >> 2;
  u16* dst = vt + ((size_t)((b*8 + h)*64 + d)*1024 + st_*64);
  #pragma unroll
  for (int t2 = 0; t2 < 2; t2++){
    int sc = (tid & 3) + t2*4;
    u16x8 o;
    #pragma unroll
    for (int j = 0; j < 8; j++) o[j] = T[(sc*8 + j)*66 + d];
    *(u16x8*)(dst + sc*8) = o;
  }
}

// ---------------- flash attention: K from qkv, V from vt, XOR-swizzled LDS ----------------
__global__ __launch_bounds__(256) void attn_kernel(const u16* __restrict__ qkv,
                                                   const u16* __restrict__ vt,
                                                   u16* __restrict__ ctx){
  __shared__ u16 Ks[64*64];
  __shared__ u16 Vs[64*64];
  __shared__ u16 Ps[4][16*72];
  int tid = threadIdx.x, l = tid & 63, w = tid >> 6;
  int hi = l >> 4, ln = l & 15;
  int orig = ((blockIdx.x & 7) << 7) | (blockIdx.x >> 3);   // XCD-contiguous (b,h)
  int qt = orig & 15, h = (orig >> 4) & 7, b = orig >> 7;
  size_t rowbase = (size_t)b * S_;

  int qrow = qt*64 + w*16 + ln;
  s16x8 aq[2];
  #pragma unroll
  for (int s = 0; s < 2; s++)
    aq[s] = *(const s16x8*)&qkv[(rowbase + qrow)*1536 + h*64 + s*32 + hi*8];

  int rl = l >> 3;                  // row within this wave's 8-row staging group
  int cg = (l & 7) ^ rl;            // pre-swizzled global 16B-chunk index
  const u16* kb = qkv + rowbase*1536 + 512 + h*64 + cg*8;
  const u16* vb = vt + (size_t)((b*8 + h)*64)*1024 + cg*8;

  f32x4 o[4];
  #pragma unroll
  for (int i = 0; i < 4; i++) o[i] = (f32x4){0.f,0.f,0.f,0.f};
  float m_[4] = {-1e30f,-1e30f,-1e30f,-1e30f};
  float l_[4] = {0.f,0.f,0.f,0.f};

  for (int kt = 0; kt < 16; kt++){
    __syncthreads();   // previous iteration's reads done before overwrite
    #pragma unroll
    for (int r2 = 0; r2 < 2; r2++){
      int rr = r2*32 + w*8;
      gload16(kb + (size_t)(kt*64 + rr + rl)*1536, &Ks[rr*64]);
      gload16(vb + (size_t)(rr + rl)*1024 + kt*64, &Vs[rr*64]);
    }
    __syncthreads();

    // S = Q K^T * 0.125   (swizzled chunk read: ((s*4+hi) ^ (row&7)))
    f32x4 sacc[4];
    #pragma unroll
    for (int nf = 0; nf < 4; nf++){
      int n = nf*16 + ln;
      f32x4 acc = (f32x4){0.f,0.f,0.f,0.f};
      #pragma unroll
      for (int s = 0; s < 2; s++){
        s16x8 bk = *(const s16x8*)&Ks[n*64 + (((s*4 + hi) ^ (n & 7)) * 8)];
        acc = __builtin_amdgcn_mfma_f32_16x16x32_bf16(aq[s], bk, acc, 0,0,0);
      }
      sacc[nf] = acc * 0.125f;
    }

    // online softmax per q-row (row = hi*4 + r)
    #pragma unroll
    for (int r = 0; r < 4; r++){
      float mx = fmaxf(fmaxf(sacc[0][r], sacc[1][r]), fmaxf(sacc[2][r], sacc[3][r]));
      #pragma unroll
      for (int msk = 1; msk < 16; msk <<= 1) mx = fmaxf(mx, __shfl_xor(mx, msk, 64));
      float mnew  = fmaxf(m_[r], mx);
      float alpha = __expf(m_[r] - mnew);
      float p0 = __expf(sacc[0][r]-mnew), p1 = __expf(sacc[1][r]-mnew);
      float p2 = __expf(sacc[2][r]-mnew), p3 = __expf(sacc[3][r]-mnew);
      float rs = p0+p1+p2+p3;
      #pragma unroll
      for (int msk = 1; msk < 16; msk <<= 1) rs += __shfl_xor(rs, msk, 64);
      l_[r] = l_[r]*alpha + rs;
      m_[r] = mnew;
      #pragma unroll
      for (int df = 0; df < 4; df++) o[df][r] *= alpha;
      int prow = hi*4 + r;
      Ps[w][prow*72 +  0 + ln] = f2b(p0);
      Ps[w][prow*72 + 16 + ln] = f2b(p1);
      Ps[w][prow*72 + 32 + ln] = f2b(p2);
      Ps[w][prow*72 + 48 + ln] = f2b(p3);
    }
    asm volatile("s_waitcnt lgkmcnt(0)" ::: "memory");
    __builtin_amdgcn_sched_barrier(0);

    // O += P V
    #pragma unroll
    for (int ks = 0; ks < 2; ks++){
      s16x8 ap = *(const s16x8*)&Ps[w][ln*72 + ks*32 + hi*8];
      #pragma unroll
      for (int df = 0; df < 4; df++){
        int n = df*16 + ln;
        s16x8 bv = *(const s16x8*)&Vs[n*64 + (((ks*4 + hi) ^ (n & 7)) * 8)];
        o[df] = __builtin_amdgcn_mfma_f32_16x16x32_bf16(ap, bv, o[df], 0,0,0);
      }
    }
  }

  // write ctx (bf16)
  #pragma unroll
  for (int df = 0; df < 4; df++)
    #pragma unroll
    for (int r = 0; r < 4; r++){
      float v = o[df][r] / l_[r];
      size_t row = rowbase + qt*64 + w*16 + (hi*4 + r);
      ctx[row*512 + h*64 + df*16 + ln] = f2b(v);
    }
}

// ---------------- LN1: out1 = LN(st + tmp), also bf16 copy ----------------
__global__ __launch_bounds__(64) void ln1_kernel(
    const float* __restrict__ tmp, const float* __restrict__ st,
    const float* __restrict__ g, const float* __restrict__ bt,
    float* __restrict__ out1, u16* __restrict__ out1b){
  int row = blockIdx.x, lane = threadIdx.x;
  size_t base = (size_t)row*512 + lane*8;
  float v[8];
  {
    const float4* tp = (const float4*)(tmp + base);
    const float4* sp = (const float4*)(st + base);
    float4 t0=tp[0], t1=tp[1], s0=sp[0], s1=sp[1];
    v[0]=t0.x+s0.x; v[1]=t0.y+s0.y; v[2]=t0.z+s0.z; v[3]=t0.w+s0.w;
    v[4]=t1.x+s1.x; v[5]=t1.y+s1.y; v[6]=t1.z+s1.z; v[7]=t1.w+s1.w;
  }
  float sum=0.f, sq=0.f;
  #pragma unroll
  for (int j=0;j<8;j++){ sum += v[j]; sq += v[j]*v[j]; }
  sum = wred_sum(sum); sq = wred_sum(sq);
  float mean = sum*(1.f/512.f);
  float var  = sq*(1.f/512.f) - mean*mean;
  float rstd = rsqrtf(fmaxf(var, 0.f) + 1e-6f);
  int c0 = lane*8;
  float y[8]; u16x8 ob;
  #pragma unroll
  for (int j=0;j<8;j++){ y[j] = (v[j]-mean)*rstd*g[c0+j] + bt[c0+j]; ob[j]=f2b(y[j]); }
  float4* op = (float4*)(out1 + base);
  op[0] = make_float4(y[0],y[1],y[2],y[3]);
  op[1] = make_float4(y[4],y[5],y[6],y[7]);
  *(u16x8*)(out1b + base) = ob;
}

// ---------------- LNf: in-place LN over DFF=2048 ----------------
__global__ __launch_bounds__(256) void lnf_kernel(
    u16* __restrict__ hbuf, const float* __restrict__ g, const float* __restrict__ bt){
  int row = blockIdx.x, tid = threadIdx.x, lane = tid & 63, wv = tid >> 6;
  size_t base = (size_t)row*2048 + tid*8;
  u16x8 x8 = *(const u16x8*)&hbuf[base];
  float v[8];
  #pragma unroll
  for (int j=0;j<8;j++) v[j] = b2f(x8[j]);
  float sum=0.f, sq=0.f;
  #pragma unroll
  for (int j=0;j<8;j++){ sum += v[j]; sq += v[j]*v[j]; }
  sum = wred_sum(sum); sq = wred_sum(sq);
  __shared__ float rs[8];
  if (lane == 0){ rs[wv] = sum; rs[4+wv] = sq; }
  __syncthreads();
  sum = rs[0]+rs[1]+rs[2]+rs[3];
  sq  = rs[4]+rs[5]+rs[6]+rs[7];
  float mean = sum*(1.f/2048.f);
  float var  = sq*(1.f/2048.f) - mean*mean;
  float rstd = rsqrtf(fmaxf(var, 0.f) + 1e-6f);
  int c0 = tid*8;
  u16x8 o;
  #pragma unroll
  for (int j=0;j<8;j++) o[j] = f2b((v[j]-mean)*rstd*g[c0+j] + bt[c0+j]);
  *(u16x8*)&hbuf[base] = o;
}

// ---------------- LN2 + ACT mix + next-step ponder dot ----------------
__global__ __launch_bounds__(64) void ln2mix_kernel(
    const float* __restrict__ tmp, const float* __restrict__ out1,
    const float* __restrict__ g, const float* __restrict__ bt,
    const float* __restrict__ uw, const float* __restrict__ aw,
    float* __restrict__ st, u16* __restrict__ stb, float* __restrict__ dotb){
  int row = blockIdx.x, lane = threadIdx.x;
  size_t base = (size_t)row*512 + lane*8;
  float v[8], sv[8];
  {
    const float4* tp = (const float4*)(tmp  + base);
    const float4* op = (const float4*)(out1 + base);
    const float4* sp = (const float4*)(st   + base);
    float4 t0=tp[0], t1=tp[1], o0=op[0], o1=op[1], s0=sp[0], s1=sp[1];
    v[0]=t0.x+o0.x; v[1]=t0.y+o0.y; v[2]=t0.z+o0.z; v[3]=t0.w+o0.w;
    v[4]=t1.x+o1.x; v[5]=t1.y+o1.y; v[6]=t1.z+o1.z; v[7]=t1.w+o1.w;
    sv[0]=s0.x; sv[1]=s0.y; sv[2]=s0.z; sv[3]=s0.w;
    sv[4]=s1.x; sv[5]=s1.y; sv[6]=s1.z; sv[7]=s1.w;
  }
  float sum=0.f, sq=0.f;
  #pragma unroll
  for (int j=0;j<8;j++){ sum += v[j]; sq += v[j]*v[j]; }
  sum = wred_sum(sum); sq = wred_sum(sq);
  float mean = sum*(1.f/512.f);
  float var  = sq*(1.f/512.f) - mean*mean;
  float rstd = rsqrtf(fmaxf(var, 0.f) + 1e-6f);
  float u = uw[row], um1 = 1.f - u;
  int c0 = lane*8;
  float z[8]; u16x8 ob;
  #pragma unroll
  for (int j=0;j<8;j++){
    float y = (v[j]-mean)*rstd*g[c0+j] + bt[c0+j];
    z[j] = y*u + sv[j]*um1;
    ob[j] = f2b(z[j]);
  }
  float4* op = (float4*)(st + base);
  op[0] = make_float4(z[0],z[1],z[2],z[3]);
  op[1] = make_float4(z[4],z[5],z[6],z[7]);
  *(u16x8*)(stb + base) = ob;
  // ponder dot for next step
  const float4* wp = (const float4*)aw + (size_t)lane*2;
  float4 w0 = wp[0], w1 = wp[1];
  float d = z[0]*w0.x + z[1]*w0.y + z[2]*w0.z + z[3]*w0.w
          + z[4]*w1.x + z[5]*w1.y + z[6]*w1.z + z[7]*w1.w;
  d = wred_sum(d);
  if (lane == 0) dotb[row] = d;
}

// ---------------- ACT halting from precomputed dot ----------------
__global__ __launch_bounds__(256) void act_kernel(
    const float* __restrict__ dotb, const float* __restrict__ ab,
    float* __restrict__ hp, float* __restrict__ rem, float* __restrict__ uw){
  int tok = blockIdx.x*256 + threadIdx.x;
  float t = dotb[tok] + ab[0];
  float p = 1.f / (1.f + expf(-t));
  float h = hp[tok], r = rem[tok];
  float still = (h < 1.f) ? 1.f : 0.f;
  float cand  = h + p*still;
  float nh  = (cand > 0.99f)  ? still : 0.f;
  float st2 = (cand <= 0.99f) ? still : 0.f;
  h += p*st2;
  r += nh*(1.f - h);
  h += nh*r;
  hp[tok] = h; rem[tok] = r;
  uw[tok] = p*st2 + nh*r;
}

// ---------------- host launch ----------------
extern "C" void kernel_launch(void* const* d_in, const int* in_sizes, int n_in,
                              void* d_out, int out_size, void* d_ws, size_t ws_size,
                              hipStream_t stream){
  const float* x     = (const float*)d_in[0];
  const float* wq    = (const float*)d_in[1];
  const float* bq    = (const float*)d_in[2];
  const float* wk    = (const float*)d_in[3];
  const float* bk    = (const float*)d_in[4];
  const float* wv    = (const float*)d_in[5];
  const float* bv    = (const float*)d_in[6];
  const float* wo    = (const float*)d_in[7];
  const float* bo    = (const float*)d_in[8];
  const float* w1    = (const float*)d_in[9];
  const float* b1    = (const float*)d_in[10];
  const float* lnf_g = (const float*)d_in[11];
  const float* lnf_b = (const float*)d_in[12];
  const float* w2    = (const float*)d_in[13];
  const float* b2    = (const float*)d_in[14];
  const float* ln1_g = (const float*)d_in[15];
  const float* ln1_b = (const float*)d_in[16];
  const float* ln2_g = (const float*)d_in[17];
  const float* ln2_b = (const float*)d_in[18];
  const float* aw    = (const float*)d_in[19];
  const float* ab    = (const float*)d_in[20];
  float* st = (float*)d_out;

  char* cur = (char*)d_ws;
  auto alloc = [&](size_t n){ void* p = cur; cur += (n + 255) & ~(size_t)255; return p; };
  u16*  wqkv_t = (u16*)alloc((size_t)1536*512*2);
  u16*  wo_t   = (u16*)alloc((size_t)512*512*2);
  u16*  w1_t   = (u16*)alloc((size_t)2048*512*2);
  u16*  w2_t   = (u16*)alloc((size_t)512*2048*2);
  float* bqkv  = (float*)alloc(1536*4);
  u16*  stb    = (u16*)alloc((size_t)M_*512*2);
  u16*  qkv    = (u16*)alloc((size_t)M_*1536*2);
  u16*  ctx    = (u16*)alloc((size_t)M_*512*2);
  u16*  out1b  = (u16*)alloc((size_t)M_*512*2);
  u16*  hbuf   = (u16*)alloc((size_t)M_*2048*2);
  float* tmp   = (float*)alloc((size_t)M_*512*4);
  float* out1  = (float*)alloc((size_t)M_*512*4);
  float* halt  = (float*)alloc((size_t)3*M_*4);
  float* dotb  = (float*)alloc((size_t)M_*4);
  float* hp = halt, *rem = halt + M_, *uw = halt + 2*M_;
  u16* vt = hbuf;   // vt lifetime (vtrans->attn) disjoint from hbuf (ffn1->ffn2)

  prep_kernel<<<2048, 256, 0, stream>>>(x, aw, st, stb, dotb);
  zero_kernel<<<96, 256, 0, stream>>>(halt);
  packb_kernel<<<6, 256, 0, stream>>>(bq, bk, bv, bqkv);
  tcast_kernel<<<64,  256, 0, stream>>>(wq, wqkv_t,            512, 512);
  tcast_kernel<<<64,  256, 0, stream>>>(wk, wqkv_t + 512*512,  512, 512);
  tcast_kernel<<<64,  256, 0, stream>>>(wv, wqkv_t + 1024*512, 512, 512);
  tcast_kernel<<<64,  256, 0, stream>>>(wo, wo_t, 512, 512);
  tcast_kernel<<<256, 256, 0, stream>>>(w1, w1_t, 512, 2048);
  tcast_kernel<<<256, 256, 0, stream>>>(w2, w2_t, 2048, 512);

  for (int s = 0; s < STEPS_; s++){
    act_kernel<<<M_/256, 256, 0, stream>>>(dotb, ab, hp, rem, uw);
    gemm_kernel<1><<<64*12, 256, 0, stream>>>(stb,   wqkv_t, bqkv, qkv,  12, 512,  1536);
    vtrans_kernel<<<1024, 256, 0, stream>>>(qkv, vt);
    attn_kernel<<<1024, 256, 0, stream>>>(qkv, vt, ctx);
    gemm_kernel<0><<<64*4,  256, 0, stream>>>(ctx,   wo_t,   bo,   tmp,  4,  512,  512);
    ln1_kernel<<<M_, 64, 0, stream>>>(tmp, st, ln1_g, ln1_b, out1, out1b);
    gemm_kernel<2><<<64*16, 256, 0, stream>>>(out1b, w1_t,   b1,   hbuf, 16, 512,  2048);
    lnf_kernel<<<M_, 256, 0, stream>>>(hbuf, lnf_g, lnf_b);
    gemm_kernel<0><<<64*4,  256, 0, stream>>>(hbuf,  w2_t,   b2,   tmp,  4,  2048, 512);
    ln2mix_kernel<<<M_, 64, 0, stream>>>(tmp, out1, ln2_g, ln2_b, uw, aw, st, stb, dotb);
  }
}

// Round 3
// 1229.988 us; speedup vs baseline: 1.3275x; 1.1030x over previous
//
#include <hip/hip_runtime.h>
#include <cstdint>
#include <cstddef>

#define B_ 8
#define S_ 1024
#define D_ 512
#define H_ 8
#define DH_ 64
#define DFF_ 2048
#define STEPS_ 6
#define M_ (B_*S_)   // 8192 tokens

typedef unsigned short u16;
typedef u16   u16x8 __attribute__((ext_vector_type(8)));
typedef short s16x8 __attribute__((ext_vector_type(8)));
typedef float f32x4 __attribute__((ext_vector_type(4)));

__device__ __forceinline__ u16 f2b(float f){
  union { float f; unsigned u; } v; v.f = f;
  unsigned r = v.u + 0x7fffu + ((v.u >> 16) & 1u);
  return (u16)(r >> 16);
}
__device__ __forceinline__ float b2f(u16 u){
  union { unsigned u; float f; } v; v.u = ((unsigned)u) << 16;
  return v.f;
}
__device__ __forceinline__ unsigned cvtpk(float lo, float hi){
  unsigned r;
  asm("v_cvt_pk_bf16_f32 %0, %1, %2" : "=v"(r) : "v"(lo), "v"(hi));
  return r;
}
__device__ __forceinline__ void gload16(const void* g, void* l){
  __builtin_amdgcn_global_load_lds(
    (const __attribute__((address_space(1))) void*)g,
    (__attribute__((address_space(3))) void*)l, 16, 0, 0);
}
__device__ __forceinline__ float wred_sum(float v){
  #pragma unroll
  for (int m = 1; m < 64; m <<= 1) v += __shfl_xor(v, m, 64);
  return v;
}

// ---------------- prep: st = x, stb = bf16(x), dotb[row] = x_row . act_w ----------------
__global__ __launch_bounds__(256) void prep_kernel(const float* __restrict__ x,
    const float* __restrict__ aw, float* __restrict__ st, u16* __restrict__ stb,
    float* __restrict__ dotb){
  int tid = threadIdx.x; int l = tid & 63; int w = tid >> 6;
  size_t i = (size_t)blockIdx.x*256 + tid;     // group of 8 elems; one wave = one row
  const float4* xp = (const float4*)x + i*2;
  float4 a = xp[0], b = xp[1];
  ((float4*)st)[i*2]   = a;
  ((float4*)st)[i*2+1] = b;
  u16x8 o;
  o[0]=f2b(a.x); o[1]=f2b(a.y); o[2]=f2b(a.z); o[3]=f2b(a.w);
  o[4]=f2b(b.x); o[5]=f2b(b.y); o[6]=f2b(b.z); o[7]=f2b(b.w);
  ((u16x8*)stb)[i] = o;
  const float4* wp = (const float4*)aw + (size_t)l*2;
  float4 w0 = wp[0], w1 = wp[1];
  float d = a.x*w0.x + a.y*w0.y + a.z*w0.z + a.w*w0.w
          + b.x*w1.x + b.y*w1.y + b.z*w1.z + b.w*w1.w;
  d = wred_sum(d);
  if (l == 0) dotb[blockIdx.x*4 + w] = d;
}

__global__ void zero_kernel(float* __restrict__ p){
  p[(size_t)blockIdx.x*256 + threadIdx.x] = 0.f;
}

// ---------------- tiled transpose-cast: W[K][N] f32 -> Wt[N][K] bf16 ----------------
__global__ __launch_bounds__(256) void tcast_kernel(const float* __restrict__ W,
    u16* __restrict__ Wt, int K, int N){
  __shared__ u16 T[64*66];
  int tid = threadIdx.x;
  int nbt = N >> 6;
  int k0 = (blockIdx.x / nbt) << 6, n0 = (blockIdx.x % nbt) << 6;
  int r = tid >> 2, c4 = tid & 3;
  const float* src = W + (size_t)(k0 + r)*N + n0 + c4*16;
  #pragma unroll
  for (int q = 0; q < 2; q++){
    float4 f0 = ((const float4*)src)[q*2], f1 = ((const float4*)src)[q*2+1];
    u16x8 t;
    t[0]=f2b(f0.x); t[1]=f2b(f0.y); t[2]=f2b(f0.z); t[3]=f2b(f0.w);
    t[4]=f2b(f1.x); t[5]=f2b(f1.y); t[6]=f2b(f1.z); t[7]=f2b(f1.w);
    *(u16x8*)&T[r*66 + c4*16 + q*8] = t;
  }
  __syncthreads();
  int n = tid >> 2;
  #pragma unroll
  for (int t2 = 0; t2 < 2; t2++){
    int sc = (tid & 3) + t2*4;
    u16x8 o;
    #pragma unroll
    for (int j = 0; j < 8; j++) o[j] = T[(sc*8 + j)*66 + n];
    *(u16x8*)&Wt[(size_t)(n0 + n)*K + k0 + sc*8] = o;
  }
}

__global__ void packb_kernel(const float* __restrict__ bq, const float* __restrict__ bk,
                             const float* __restrict__ bv, float* __restrict__ bqkv){
  int i = blockIdx.x*256 + threadIdx.x;
  if (i < 512)       bqkv[i] = bq[i];
  else if (i < 1024) bqkv[i] = bk[i-512];
  else if (i < 1536) bqkv[i] = bv[i-1024];
}

// ---------------- GEMM: C = A[M][K](bf16) * Bt[N][K](bf16)^T + bias ----------------
// EPI: 0 = f32 out, 1 = bf16 out, 2 = bf16 relu out.  BM in {64,128}, BN=128.
template<int EPI, int BM>
__global__ __launch_bounds__(256) void gemm_kernel(
    const u16* __restrict__ A, const u16* __restrict__ Bt,
    const float* __restrict__ bias, void* __restrict__ C,
    int ntn, int K, int ldo){
  __shared__ u16 As[BM*32];
  __shared__ u16 Bs[128*32];
  int tid = threadIdx.x; int lane = tid & 63; int w = tid >> 6;
  int hi = lane >> 4, ln = lane & 15;
  constexpr int NF  = (BM == 128) ? 4 : 2;   // N-frags per wave
  constexpr int WNW = (BM == 128) ? 64 : 32; // wave N width
  int wm = (BM == 128) ? (w >> 1) : 0;
  int wn = (BM == 128) ? (w & 1)  : w;
  int tn = blockIdx.x % ntn, tm = blockIdx.x / ntn;
  int m0 = tm*BM, n0 = tn*128;
  int rl = lane >> 2, cl = lane & 3;
  int cg = cl ^ (rl & 3);                    // pre-swizzled global chunk
  size_t aoff, boff;
  if (BM == 128) aoff = (size_t)(m0 + w*32 + rl)*K + cg*8;
  else           aoff = (size_t)(m0 + w*16 + rl)*K + cg*8;
  boff = (size_t)(n0 + w*32 + rl)*K + cg*8;
  int fsw = (ln & 3);                        // frag-read swizzle
  f32x4 acc[4][NF];
  #pragma unroll
  for (int i=0;i<4;i++)
    #pragma unroll
    for (int j=0;j<NF;j++) acc[i][j] = (f32x4){0.f,0.f,0.f,0.f};

  for (int k0 = 0; k0 < K; k0 += 32){
    if (BM == 128){
      gload16(A + aoff + k0,                &As[w*1024]);
      gload16(A + aoff + (size_t)16*K + k0, &As[w*1024 + 512]);
    } else {
      gload16(A + aoff + k0,                &As[w*512]);
    }
    gload16(Bt + boff + k0,                 &Bs[w*1024]);
    gload16(Bt + boff + (size_t)16*K + k0,  &Bs[w*1024 + 512]);
    __syncthreads();
    s16x8 af[4], bf[NF];
    #pragma unroll
    for (int mi=0;mi<4;mi++){
      int row = wm*64 + mi*16 + ln;
      af[mi] = *(const s16x8*)&As[row*32 + ((hi ^ fsw)*8)];
    }
    #pragma unroll
    for (int ni=0;ni<NF;ni++){
      int brow = wn*WNW + ni*16 + ln;
      bf[ni] = *(const s16x8*)&Bs[brow*32 + ((hi ^ fsw)*8)];
    }
    #pragma unroll
    for (int mi=0;mi<4;mi++)
      #pragma unroll
      for (int ni=0;ni<NF;ni++)
        acc[mi][ni] = __builtin_amdgcn_mfma_f32_16x16x32_bf16(af[mi], bf[ni], acc[mi][ni], 0,0,0);
    __syncthreads();
  }

  #pragma unroll
  for (int mi=0;mi<4;mi++){
    int row0 = m0 + wm*64 + mi*16 + hi*4;
    #pragma unroll
    for (int ni=0;ni<NF;ni++){
      int col = n0 + wn*WNW + ni*16 + ln;
      float bc = bias[col];
      #pragma unroll
      for (int r=0;r<4;r++){
        float v = acc[mi][ni][r] + bc;
        if (EPI == 2) v = fmaxf(v, 0.f);
        if (EPI == 0) ((float*)C)[(size_t)(row0+r)*ldo + col] = v;
        else          ((u16*) C)[(size_t)(row0+r)*ldo + col] = f2b(v);
      }
    }
  }
}

// ---------------- vtrans: qkv V-part [M][1536] -> vt[(b*8+h)*64+d][1024] ----------------
__global__ __launch_bounds__(256) void vtrans_kernel(const u16* __restrict__ qkv,
                                                     u16* __restrict__ vt){
  __shared__ u16 T[64*66];
  int tid = threadIdx.x;
  int bid = blockIdx.x;
  int st_ = bid & 15, h = (bid >> 4) & 7, b = bid >> 7;
  int s = tid >> 2, c4 = tid & 3;
  const u16* src = qkv + ((size_t)(b*1024 + st_*64 + s)*1536 + 1024 + h*64);
  *(u16x8*)&T[s*66 + c4*8]        = *(const u16x8*)(src + c4*8);
  *(u16x8*)&T[s*66 + (c4+4)*8]    = *(const u16x8*)(src + (c4+4)*8);
  __syncthreads();
  int d = tid >> 2;
  u16* dst = vt + ((size_t)((b*8 + h)*64 + d)*1024 + st_*64);
  #pragma unroll
  for (int t2 = 0; t2 < 2; t2++){
    int sc = (tid & 3) + t2*4;
    u16x8 o;
    #pragma unroll
    for (int j = 0; j < 8; j++) o[j] = T[(sc*8 + j)*66 + d];
    *(u16x8*)(dst + sc*8) = o;
  }
}

// ---------------- flash attention, swapped QK^T, in-register softmax ----------------
__global__ __launch_bounds__(256) void attn_kernel(const u16* __restrict__ qkv,
                                                   const u16* __restrict__ vt,
                                                   u16* __restrict__ ctx){
  __shared__ u16 Ks[2][64*64];
  __shared__ u16 Vs[2][64*64];
  int tid = threadIdx.x, l = tid & 63, w = tid >> 6;
  int hi = l >> 4, ln = l & 15;
  int orig = ((blockIdx.x & 7) << 7) | (blockIdx.x >> 3);   // XCD-contiguous (b)
  int qt = orig & 15, h = (orig >> 4) & 7, b = orig >> 7;
  size_t rowbase = (size_t)b * S_;

  // Q as B-operand fragments (n = q = ln), held for whole kernel
  int qrow = qt*64 + w*16 + ln;
  s16x8 bq[2];
  #pragma unroll
  for (int s = 0; s < 2; s++)
    bq[s] = *(const s16x8*)&qkv[(rowbase + qrow)*1536 + h*64 + s*32 + hi*8];

  int rl = l >> 3;
  int cg = (l & 7) ^ rl;            // pre-swizzled global 16B-chunk index
  const u16* kb = qkv + rowbase*1536 + 512 + h*64 + cg*8;
  const u16* vb = vt + (size_t)((b*8 + h)*64)*1024 + cg*8;

  f32x4 o[4];
  #pragma unroll
  for (int i = 0; i < 4; i++) o[i] = (f32x4){0.f,0.f,0.f,0.f};
  float m_ = -1e30f, l_ = 0.f;

  #define STAGE(buf, kt) do { \
    _Pragma("unroll") \
    for (int r2 = 0; r2 < 2; r2++){ \
      int rr = r2*32 + w*8; \
      gload16(kb + (size_t)((kt)*64 + rr + rl)*1536, &Ks[buf][rr*64]); \
      gload16(vb + (size_t)(rr + rl)*1024 + (kt)*64, &Vs[buf][rr*64]); \
    } } while(0)

  STAGE(0, 0);
  STAGE(1, 1);
  asm volatile("s_waitcnt vmcnt(4)" ::: "memory");   // tile 0 staged
  __builtin_amdgcn_s_barrier();
  __builtin_amdgcn_sched_barrier(0);

  for (int kt = 0; kt < 16; kt++){
    int cur = kt & 1;
    // ---- read all fragments of cur into registers ----
    s16x8 ak[4][2], av[4][2];
    #pragma unroll
    for (int nf = 0; nf < 4; nf++){
      int n = nf*16 + ln;
      int swz = n & 7;
      #pragma unroll
      for (int s = 0; s < 2; s++){
        ak[nf][s] = *(const s16x8*)&Ks[cur][n*64 + (((s*4 + hi) ^ swz)*8)];
        av[nf][s] = *(const s16x8*)&Vs[cur][n*64 + (((s*4 + hi) ^ swz)*8)];
      }
    }
    asm volatile("s_waitcnt lgkmcnt(0)" ::: "memory");
    __builtin_amdgcn_sched_barrier(0);
    __builtin_amdgcn_s_barrier();          // all waves done READING cur
    __builtin_amdgcn_sched_barrier(0);
    if (kt < 14) STAGE(cur, kt+2);         // overwrite cur with tile kt+2

    // ---- S^T = K Q^T : sacc[nf][r] = S[k=nf*16+hi*4+r][q=ln] (unscaled) ----
    f32x4 sacc[4];
    #pragma unroll
    for (int nf = 0; nf < 4; nf++){
      f32x4 acc = (f32x4){0.f,0.f,0.f,0.f};
      #pragma unroll
      for (int s = 0; s < 2; s++)
        acc = __builtin_amdgcn_mfma_f32_16x16x32_bf16(ak[nf][s], bq[s], acc, 0,0,0);
      sacc[nf] = acc;
    }

    // ---- in-register online softmax (per-lane q = ln) ----
    float mx = sacc[0][0];
    #pragma unroll
    for (int nf = 0; nf < 4; nf++)
      #pragma unroll
      for (int r = 0; r < 4; r++) mx = fmaxf(mx, sacc[nf][r]);
    mx = fmaxf(mx, __shfl_xor(mx, 16, 64));
    mx = fmaxf(mx, __shfl_xor(mx, 32, 64));
    float mnew  = fmaxf(m_, mx * 0.125f);
    float alpha = __expf(m_ - mnew);
    float p[4][4];
    float rs = 0.f;
    #pragma unroll
    for (int nf = 0; nf < 4; nf++)
      #pragma unroll
      for (int r = 0; r < 4; r++){
        p[nf][r] = __expf(fmaf(sacc[nf][r], 0.125f, -mnew));
        rs += p[nf][r];
      }
    rs += __shfl_xor(rs, 16, 64);
    rs += __shfl_xor(rs, 32, 64);
    l_ = l_*alpha + rs;
    m_ = mnew;
    #pragma unroll
    for (int df = 0; df < 4; df++) o[df] *= alpha;

    // ---- pack P to bf16 pairs: W0/W1[nf] cover k = nf*16+hi*4+{0,1}/{2,3} ----
    unsigned W0[4], W1[4];
    #pragma unroll
    for (int nf = 0; nf < 4; nf++){
      W0[nf] = cvtpk(p[nf][0], p[nf][1]);
      W1[nf] = cvtpk(p[nf][2], p[nf][3]);
    }

    // ---- redistribute to PV B-fragments (16 shfl + selects) ----
    unsigned bw[2][4];
    {
      int base = (hi & 1) * 32 + ln;
      bool sel = (hi < 2);
      #pragma unroll
      for (int pat = 0; pat < 2; pat++){
        int src = base + pat*16;
        unsigned a0 = __shfl((int)W0[0], src, 64);
        unsigned a1 = __shfl((int)W0[1], src, 64);
        unsigned a2 = __shfl((int)W0[2], src, 64);
        unsigned a3 = __shfl((int)W0[3], src, 64);
        unsigned c0 = __shfl((int)W1[0], src, 64);
        unsigned c1 = __shfl((int)W1[1], src, 64);
        unsigned c2 = __shfl((int)W1[2], src, 64);
        unsigned c3 = __shfl((int)W1[3], src, 64);
        bw[0][pat*2+0] = sel ? a0 : a1;
        bw[0][pat*2+1] = sel ? c0 : c1;
        bw[1][pat*2+0] = sel ? a2 : a3;
        bw[1][pat*2+1] = sel ? c2 : c3;
      }
    }

    // ---- O^T += V^T P : o[df][r] = O[d=df*16+hi*4+r][q=ln] ----
    #pragma unroll
    for (int s = 0; s < 2; s++){
      union { unsigned u[4]; s16x8 v; } bp;
      bp.u[0] = bw[s][0]; bp.u[1] = bw[s][1];
      bp.u[2] = bw[s][2]; bp.u[3] = bw[s][3];
      #pragma unroll
      for (int df = 0; df < 4; df++)
        o[df] = __builtin_amdgcn_mfma_f32_16x16x32_bf16(av[df][s], bp.v, o[df], 0,0,0);
    }

    // ---- next-buffer staging complete before its reads ----
    if (kt < 15){
      if (kt < 14) asm volatile("s_waitcnt vmcnt(4)" ::: "memory");
      else         asm volatile("s_waitcnt vmcnt(0)" ::: "memory");
      __builtin_amdgcn_s_barrier();
      __builtin_amdgcn_sched_barrier(0);
    }
  }
  #undef STAGE

  // ---- coalesced ctx write via per-wave LDS bounce ----
  __builtin_amdgcn_s_barrier();            // all waves done with K/V LDS
  float inv = 1.f / l_;
  u16* ob = ((u16*)Ks) + w*1152;           // [16 q][72 d] per wave
  #pragma unroll
  for (int df = 0; df < 4; df++){
    unsigned w0 = cvtpk(o[df][0]*inv, o[df][1]*inv);
    unsigned w1 = cvtpk(o[df][2]*inv, o[df][3]*inv);
    *(unsigned*)&ob[ln*72 + df*16 + hi*4]     = w0;
    *(unsigned*)&ob[ln*72 + df*16 + hi*4 + 2] = w1;
  }
  asm volatile("s_waitcnt lgkmcnt(0)" ::: "memory");
  __builtin_amdgcn_sched_barrier(0);
  int r2 = l >> 2, c2 = (l & 3) * 16;
  uint4 q0 = *(uint4*)&ob[r2*72 + c2];
  uint4 q1 = *(uint4*)&ob[r2*72 + c2 + 8];
  size_t row = rowbase + qt*64 + w*16 + r2;
  *(uint4*)&ctx[row*512 + h*64 + c2]     = q0;
  *(uint4*)&ctx[row*512 + h*64 + c2 + 8] = q1;
}

// ---------------- LN1: out1 = LN(st + tmp), also bf16 copy ----------------
__global__ __launch_bounds__(64) void ln1_kernel(
    const float* __restrict__ tmp, const float* __restrict__ st,
    const float* __restrict__ g, const float* __restrict__ bt,
    float* __restrict__ out1, u16* __restrict__ out1b){
  int row = blockIdx.x, lane = threadIdx.x;
  size_t base = (size_t)row*512 + lane*8;
  float v[8];
  {
    const float4* tp = (const float4*)(tmp + base);
    const float4* sp = (const float4*)(st + base);
    float4 t0=tp[0], t1=tp[1], s0=sp[0], s1=sp[1];
    v[0]=t0.x+s0.x; v[1]=t0.y+s0.y; v[2]=t0.z+s0.z; v[3]=t0.w+s0.w;
    v[4]=t1.x+s1.x; v[5]=t1.y+s1.y; v[6]=t1.z+s1.z; v[7]=t1.w+s1.w;
  }
  float sum=0.f, sq=0.f;
  #pragma unroll
  for (int j=0;j<8;j++){ sum += v[j]; sq += v[j]*v[j]; }
  sum = wred_sum(sum); sq = wred_sum(sq);
  float mean = sum*(1.f/512.f);
  float var  = sq*(1.f/512.f) - mean*mean;
  float rstd = rsqrtf(fmaxf(var, 0.f) + 1e-6f);
  int c0 = lane*8;
  float y[8]; u16x8 ob;
  #pragma unroll
  for (int j=0;j<8;j++){ y[j] = (v[j]-mean)*rstd*g[c0+j] + bt[c0+j]; ob[j]=f2b(y[j]); }
  float4* op = (float4*)(out1 + base);
  op[0] = make_float4(y[0],y[1],y[2],y[3]);
  op[1] = make_float4(y[4],y[5],y[6],y[7]);
  *(u16x8*)(out1b + base) = ob;
}

// ---------------- LNf: in-place LN over DFF=2048 ----------------
__global__ __launch_bounds__(256) void lnf_kernel(
    u16* __restrict__ hbuf, const float* __restrict__ g, const float* __restrict__ bt){
  int row = blockIdx.x, tid = threadIdx.x, lane = tid & 63, wv = tid >> 6;
  size_t base = (size_t)row*2048 + tid*8;
  u16x8 x8 = *(const u16x8*)&hbuf[base];
  float v[8];
  #pragma unroll
  for (int j=0;j<8;j++) v[j] = b2f(x8[j]);
  float sum=0.f, sq=0.f;
  #pragma unroll
  for (int j=0;j<8;j++){ sum += v[j]; sq += v[j]*v[j]; }
  sum = wred_sum(sum); sq = wred_sum(sq);
  __shared__ float rs[8];
  if (lane == 0){ rs[wv] = sum; rs[4+wv] = sq; }
  __syncthreads();
  sum = rs[0]+rs[1]+rs[2]+rs[3];
  sq  = rs[4]+rs[5]+rs[6]+rs[7];
  float mean = sum*(1.f/2048.f);
  float var  = sq*(1.f/2048.f) - mean*mean;
  float rstd = rsqrtf(fmaxf(var, 0.f) + 1e-6f);
  int c0 = tid*8;
  u16x8 o;
  #pragma unroll
  for (int j=0;j<8;j++) o[j] = f2b((v[j]-mean)*rstd*g[c0+j] + bt[c0+j]);
  *(u16x8*)&hbuf[base] = o;
}

// ---------------- LN2 + ACT mix + next-step ponder dot ----------------
__global__ __launch_bounds__(64) void ln2mix_kernel(
    const float* __restrict__ tmp, const float* __restrict__ out1,
    const float* __restrict__ g, const float* __restrict__ bt,
    const float* __restrict__ uw, const float* __restrict__ aw,
    float* __restrict__ st, u16* __restrict__ stb, float* __restrict__ dotb){
  int row = blockIdx.x, lane = threadIdx.x;
  size_t base = (size_t)row*512 + lane*8;
  float v[8], sv[8];
  {
    const float4* tp = (const float4*)(tmp  + base);
    const float4* op = (const float4*)(out1 + base);
    const float4* sp = (const float4*)(st   + base);
    float4 t0=tp[0], t1=tp[1], o0=op[0], o1=op[1], s0=sp[0], s1=sp[1];
    v[0]=t0.x+o0.x; v[1]=t0.y+o0.y; v[2]=t0.z+o0.z; v[3]=t0.w+o0.w;
    v[4]=t1.x+o1.x; v[5]=t1.y+o1.y; v[6]=t1.z+o1.z; v[7]=t1.w+o1.w;
    sv[0]=s0.x; sv[1]=s0.y; sv[2]=s0.z; sv[3]=s0.w;
    sv[4]=s1.x; sv[5]=s1.y; sv[6]=s1.z; sv[7]=s1.w;
  }
  float sum=0.f, sq=0.f;
  #pragma unroll
  for (int j=0;j<8;j++){ sum += v[j]; sq += v[j]*v[j]; }
  sum = wred_sum(sum); sq = wred_sum(sq);
  float mean = sum*(1.f/512.f);
  float var  = sq*(1.f/512.f) - mean*mean;
  float rstd = rsqrtf(fmaxf(var, 0.f) + 1e-6f);
  float u = uw[row], um1 = 1.f - u;
  int c0 = lane*8;
  float z[8]; u16x8 ob;
  #pragma unroll
  for (int j=0;j<8;j++){
    float y = (v[j]-mean)*rstd*g[c0+j] + bt[c0+j];
    z[j] = y*u + sv[j]*um1;
    ob[j] = f2b(z[j]);
  }
  float4* op = (float4*)(st + base);
  op[0] = make_float4(z[0],z[1],z[2],z[3]);
  op[1] = make_float4(z[4],z[5],z[6],z[7]);
  *(u16x8*)(stb + base) = ob;
  const float4* wp = (const float4*)aw + (size_t)lane*2;
  float4 w0 = wp[0], w1 = wp[1];
  float d = z[0]*w0.x + z[1]*w0.y + z[2]*w0.z + z[3]*w0.w
          + z[4]*w1.x + z[5]*w1.y + z[6]*w1.z + z[7]*w1.w;
  d = wred_sum(d);
  if (lane == 0) dotb[row] = d;
}

// ---------------- ACT halting from precomputed dot ----------------
__global__ __launch_bounds__(256) void act_kernel(
    const float* __restrict__ dotb, const float* __restrict__ ab,
    float* __restrict__ hp, float* __restrict__ rem, float* __restrict__ uw){
  int tok = blockIdx.x*256 + threadIdx.x;
  float t = dotb[tok] + ab[0];
  float p = 1.f / (1.f + expf(-t));
  float h = hp[tok], r = rem[tok];
  float still = (h < 1.f) ? 1.f : 0.f;
  float cand  = h + p*still;
  float nh  = (cand > 0.99f)  ? still : 0.f;
  float st2 = (cand <= 0.99f) ? still : 0.f;
  h += p*st2;
  r += nh*(1.f - h);
  h += nh*r;
  hp[tok] = h; rem[tok] = r;
  uw[tok] = p*st2 + nh*r;
}

// ---------------- host launch ----------------
extern "C" void kernel_launch(void* const* d_in, const int* in_sizes, int n_in,
                              void* d_out, int out_size, void* d_ws, size_t ws_size,
                              hipStream_t stream){
  const float* x     = (const float*)d_in[0];
  const float* wq    = (const float*)d_in[1];
  const float* bq    = (const float*)d_in[2];
  const float* wk    = (const float*)d_in[3];
  const float* bk    = (const float*)d_in[4];
  const float* wv    = (const float*)d_in[5];
  const float* bv    = (const float*)d_in[6];
  const float* wo    = (const float*)d_in[7];
  const float* bo    = (const float*)d_in[8];
  const float* w1    = (const float*)d_in[9];
  const float* b1    = (const float*)d_in[10];
  const float* lnf_g = (const float*)d_in[11];
  const float* lnf_b = (const float*)d_in[12];
  const float* w2    = (const float*)d_in[13];
  const float* b2    = (const float*)d_in[14];
  const float* ln1_g = (const float*)d_in[15];
  const float* ln1_b = (const float*)d_in[16];
  const float* ln2_g = (const float*)d_in[17];
  const float* ln2_b = (const float*)d_in[18];
  const float* aw    = (const float*)d_in[19];
  const float* ab    = (const float*)d_in[20];
  float* st = (float*)d_out;

  char* cur = (char*)d_ws;
  auto alloc = [&](size_t n){ void* p = cur; cur += (n + 255) & ~(size_t)255; return p; };
  u16*  wqkv_t = (u16*)alloc((size_t)1536*512*2);
  u16*  wo_t   = (u16*)alloc((size_t)512*512*2);
  u16*  w1_t   = (u16*)alloc((size_t)2048*512*2);
  u16*  w2_t   = (u16*)alloc((size_t)512*2048*2);
  float* bqkv  = (float*)alloc(1536*4);
  u16*  stb    = (u16*)alloc((size_t)M_*512*2);
  u16*  qkv    = (u16*)alloc((size_t)M_*1536*2);
  u16*  ctx    = (u16*)alloc((size_t)M_*512*2);
  u16*  out1b  = (u16*)alloc((size_t)M_*512*2);
  u16*  hbuf   = (u16*)alloc((size_t)M_*2048*2);
  float* tmp   = (float*)alloc((size_t)M_*512*4);
  float* out1  = (float*)alloc((size_t)M_*512*4);
  float* halt  = (float*)alloc((size_t)3*M_*4);
  float* dotb  = (float*)alloc((size_t)M_*4);
  float* hp = halt, *rem = halt + M_, *uw = halt + 2*M_;
  u16* vt = hbuf;   // vt lifetime (vtrans->attn) disjoint from hbuf (ffn1->ffn2)

  prep_kernel<<<2048, 256, 0, stream>>>(x, aw, st, stb, dotb);
  zero_kernel<<<96, 256, 0, stream>>>(halt);
  packb_kernel<<<6, 256, 0, stream>>>(bq, bk, bv, bqkv);
  tcast_kernel<<<64,  256, 0, stream>>>(wq, wqkv_t,            512, 512);
  tcast_kernel<<<64,  256, 0, stream>>>(wk, wqkv_t + 512*512,  512, 512);
  tcast_kernel<<<64,  256, 0, stream>>>(wv, wqkv_t + 1024*512, 512, 512);
  tcast_kernel<<<64,  256, 0, stream>>>(wo, wo_t, 512, 512);
  tcast_kernel<<<256, 256, 0, stream>>>(w1, w1_t, 512, 2048);
  tcast_kernel<<<256, 256, 0, stream>>>(w2, w2_t, 2048, 512);

  for (int s = 0; s < STEPS_; s++){
    act_kernel<<<M_/256, 256, 0, stream>>>(dotb, ab, hp, rem, uw);
    gemm_kernel<1,128><<<64*12, 256, 0, stream>>>(stb,   wqkv_t, bqkv, qkv,  12, 512,  1536);
    vtrans_kernel<<<1024, 256, 0, stream>>>(qkv, vt);
    attn_kernel<<<1024, 256, 0, stream>>>(qkv, vt, ctx);
    gemm_kernel<0,64><<<128*4, 256, 0, stream>>>(ctx,   wo_t,   bo,   tmp,  4,  512,  512);
    ln1_kernel<<<M_, 64, 0, stream>>>(tmp, st, ln1_g, ln1_b, out1, out1b);
    gemm_kernel<2,128><<<64*16, 256, 0, stream>>>(out1b, w1_t,   b1,   hbuf, 16, 512,  2048);
    lnf_kernel<<<M_, 256, 0, stream>>>(hbuf, lnf_g, lnf_b);
    gemm_kernel<0,64><<<128*4, 256, 0, stream>>>(hbuf,  w2_t,   b2,   tmp,  4,  2048, 512);
    ln2mix_kernel<<<M_, 64, 0, stream>>>(tmp, out1, ln2_g, ln2_b, uw, aw, st, stb, dotb);
  }
}

// Round 4
// 1131.395 us; speedup vs baseline: 1.4432x; 1.0871x over previous
//
#include <hip/hip_runtime.h>
#include <cstdint>
#include <cstddef>

#define B_ 8
#define S_ 1024
#define D_ 512
#define H_ 8
#define DH_ 64
#define DFF_ 2048
#define STEPS_ 6
#define M_ (B_*S_)   // 8192 tokens

typedef unsigned short u16;
typedef u16   u16x8 __attribute__((ext_vector_type(8)));
typedef short s16x8 __attribute__((ext_vector_type(8)));
typedef float f32x4 __attribute__((ext_vector_type(4)));

__device__ __forceinline__ u16 f2b(float f){
  union { float f; unsigned u; } v; v.f = f;
  unsigned r = v.u + 0x7fffu + ((v.u >> 16) & 1u);
  return (u16)(r >> 16);
}
__device__ __forceinline__ float b2f(u16 u){
  union { unsigned u; float f; } v; v.u = ((unsigned)u) << 16;
  return v.f;
}
__device__ __forceinline__ unsigned cvtpk(float lo, float hi){
  unsigned r;
  asm("v_cvt_pk_bf16_f32 %0, %1, %2" : "=v"(r) : "v"(lo), "v"(hi));
  return r;
}
__device__ __forceinline__ void gload16(const void* g, void* l){
  __builtin_amdgcn_global_load_lds(
    (const __attribute__((address_space(1))) void*)g,
    (__attribute__((address_space(3))) void*)l, 16, 0, 0);
}
__device__ __forceinline__ float wred_sum(float v){
  #pragma unroll
  for (int m = 1; m < 64; m <<= 1) v += __shfl_xor(v, m, 64);
  return v;
}

// ---------------- prep: st = x, stb = bf16(x), dotb[row] = x_row . act_w ----------------
__global__ __launch_bounds__(256) void prep_kernel(const float* __restrict__ x,
    const float* __restrict__ aw, float* __restrict__ st, u16* __restrict__ stb,
    float* __restrict__ dotb){
  int tid = threadIdx.x; int l = tid & 63; int w = tid >> 6;
  size_t i = (size_t)blockIdx.x*256 + tid;     // group of 8 elems; one wave = one row
  const float4* xp = (const float4*)x + i*2;
  float4 a = xp[0], b = xp[1];
  ((float4*)st)[i*2]   = a;
  ((float4*)st)[i*2+1] = b;
  u16x8 o;
  o[0]=f2b(a.x); o[1]=f2b(a.y); o[2]=f2b(a.z); o[3]=f2b(a.w);
  o[4]=f2b(b.x); o[5]=f2b(b.y); o[6]=f2b(b.z); o[7]=f2b(b.w);
  ((u16x8*)stb)[i] = o;
  const float4* wp = (const float4*)aw + (size_t)l*2;
  float4 w0 = wp[0], w1 = wp[1];
  float d = a.x*w0.x + a.y*w0.y + a.z*w0.z + a.w*w0.w
          + b.x*w1.x + b.y*w1.y + b.z*w1.z + b.w*w1.w;
  d = wred_sum(d);
  if (l == 0) dotb[blockIdx.x*4 + w] = d;
}

__global__ void zero_kernel(float* __restrict__ p){
  p[(size_t)blockIdx.x*256 + threadIdx.x] = 0.f;
}

// ---------------- tiled transpose-cast: W[K][N] f32 -> Wt[N][K] bf16 ----------------
__global__ __launch_bounds__(256) void tcast_kernel(const float* __restrict__ W,
    u16* __restrict__ Wt, int K, int N){
  __shared__ u16 T[64*66];
  int tid = threadIdx.x;
  int nbt = N >> 6;
  int k0 = (blockIdx.x / nbt) << 6, n0 = (blockIdx.x % nbt) << 6;
  int r = tid >> 2, c4 = tid & 3;
  const float* src = W + (size_t)(k0 + r)*N + n0 + c4*16;
  #pragma unroll
  for (int q = 0; q < 2; q++){
    float4 f0 = ((const float4*)src)[q*2], f1 = ((const float4*)src)[q*2+1];
    u16x8 t;
    t[0]=f2b(f0.x); t[1]=f2b(f0.y); t[2]=f2b(f0.z); t[3]=f2b(f0.w);
    t[4]=f2b(f1.x); t[5]=f2b(f1.y); t[6]=f2b(f1.z); t[7]=f2b(f1.w);
    *(u16x8*)&T[r*66 + c4*16 + q*8] = t;
  }
  __syncthreads();
  int n = tid >> 2;
  #pragma unroll
  for (int t2 = 0; t2 < 2; t2++){
    int sc = (tid & 3) + t2*4;
    u16x8 o;
    #pragma unroll
    for (int j = 0; j < 8; j++) o[j] = T[(sc*8 + j)*66 + n];
    *(u16x8*)&Wt[(size_t)(n0 + n)*K + k0 + sc*8] = o;
  }
}

__global__ void packb_kernel(const float* __restrict__ bq, const float* __restrict__ bk,
                             const float* __restrict__ bv, float* __restrict__ bqkv){
  int i = blockIdx.x*256 + threadIdx.x;
  if (i < 512)       bqkv[i] = bq[i];
  else if (i < 1024) bqkv[i] = bk[i-512];
  else if (i < 1536) bqkv[i] = bv[i-1024];
}

// ---------------- GEMM: C = A[M][K](bf16) * Bt[N][K](bf16)^T + bias ----------------
// EPI: 0 = f32 out, 1 = qkv mode (bf16 out; V-blocks n0>=1024 write transposed vt only),
//      2 = bf16 relu out.  BM in {64,128}, BN=128.  Double-buffered, counted vmcnt.
template<int EPI, int BM>
__global__ __launch_bounds__(256) void gemm_kernel(
    const u16* __restrict__ A, const u16* __restrict__ Bt,
    const float* __restrict__ bias, void* __restrict__ C,
    int ntn, int K, int ldo, u16* __restrict__ vt){
  __shared__ u16 As[2][BM*32];
  __shared__ u16 Bs[2][128*32];
  int tid = threadIdx.x; int lane = tid & 63; int w = tid >> 6;
  int hi = lane >> 4, ln = lane & 15;
  constexpr int NF  = (BM == 128) ? 4 : 2;   // N-frags per wave
  constexpr int WNW = (BM == 128) ? 64 : 32; // wave N width
  int wm = (BM == 128) ? (w >> 1) : 0;
  int wn = (BM == 128) ? (w & 1)  : w;
  int tn = blockIdx.x % ntn, tm = blockIdx.x / ntn;
  int m0 = tm*BM, n0 = tn*128;
  int rl = lane >> 2, cl = lane & 3;
  int cg = cl ^ (rl & 3);                    // pre-swizzled global chunk
  size_t aoff, boff;
  if (BM == 128) aoff = (size_t)(m0 + w*32 + rl)*K + cg*8;
  else           aoff = (size_t)(m0 + w*16 + rl)*K + cg*8;
  boff = (size_t)(n0 + w*32 + rl)*K + cg*8;
  int fsw = (ln & 3);                        // frag-read swizzle
  f32x4 acc[4][NF];
  #pragma unroll
  for (int i=0;i<4;i++)
    #pragma unroll
    for (int j=0;j<NF;j++) acc[i][j] = (f32x4){0.f,0.f,0.f,0.f};

  int nk = K >> 5;

  #define GSTAGE(buf, kt) do { \
    size_t kof = (size_t)(kt)*32; \
    if (BM == 128){ \
      gload16(A + aoff + kof,                &As[buf][w*1024]); \
      gload16(A + aoff + (size_t)16*K + kof, &As[buf][w*1024 + 512]); \
    } else { \
      gload16(A + aoff + kof,                &As[buf][w*512]); \
    } \
    gload16(Bt + boff + kof,                 &Bs[buf][w*1024]); \
    gload16(Bt + boff + (size_t)16*K + kof,  &Bs[buf][w*1024 + 512]); \
  } while(0)

  #define WAITN() do { \
    if (BM == 128) asm volatile("s_waitcnt vmcnt(4)" ::: "memory"); \
    else           asm volatile("s_waitcnt vmcnt(3)" ::: "memory"); \
  } while(0)

  GSTAGE(0, 0);
  GSTAGE(1, 1);
  WAITN();
  __builtin_amdgcn_s_barrier();
  __builtin_amdgcn_sched_barrier(0);

  for (int kt = 0; kt < nk; kt++){
    int cur = kt & 1;
    s16x8 af[4], bf[NF];
    #pragma unroll
    for (int mi=0;mi<4;mi++){
      int row = wm*64 + mi*16 + ln;
      af[mi] = *(const s16x8*)&As[cur][row*32 + ((hi ^ fsw)*8)];
    }
    #pragma unroll
    for (int ni=0;ni<NF;ni++){
      int brow = wn*WNW + ni*16 + ln;
      bf[ni] = *(const s16x8*)&Bs[cur][brow*32 + ((hi ^ fsw)*8)];
    }
    asm volatile("s_waitcnt lgkmcnt(0)" ::: "memory");
    __builtin_amdgcn_sched_barrier(0);
    __builtin_amdgcn_s_barrier();          // all waves done READING cur
    __builtin_amdgcn_sched_barrier(0);
    if (kt < nk-2) GSTAGE(cur, kt+2);

    __builtin_amdgcn_s_setprio(1);
    #pragma unroll
    for (int mi=0;mi<4;mi++)
      #pragma unroll
      for (int ni=0;ni<NF;ni++)
        acc[mi][ni] = __builtin_amdgcn_mfma_f32_16x16x32_bf16(af[mi], bf[ni], acc[mi][ni], 0,0,0);
    __builtin_amdgcn_s_setprio(0);

    if (kt < nk-1){
      if (kt < nk-2) WAITN();
      else           asm volatile("s_waitcnt vmcnt(0)" ::: "memory");
      __builtin_amdgcn_s_barrier();
      __builtin_amdgcn_sched_barrier(0);
    }
  }
  #undef GSTAGE
  #undef WAITN

  if (EPI == 1 && n0 >= 1024){
    // V-blocks: write transposed into vt[(b*8+h)*64+d][1024] only
    #pragma unroll
    for (int mi=0;mi<4;mi++){
      int row0 = m0 + wm*64 + mi*16 + hi*4;
      int b = row0 >> 10, s0 = row0 & 1023;
      #pragma unroll
      for (int ni=0;ni<NF;ni++){
        int vcol = (n0 - 1024) + wn*WNW + ni*16 + ln;
        int h = vcol >> 6, d = vcol & 63;
        float bc = bias[1024 + vcol];
        uint2 pk;
        pk.x = cvtpk(acc[mi][ni][0] + bc, acc[mi][ni][1] + bc);
        pk.y = cvtpk(acc[mi][ni][2] + bc, acc[mi][ni][3] + bc);
        *(uint2*)&vt[((size_t)((b*8 + h)*64 + d))*1024 + s0] = pk;
      }
    }
    return;
  }

  #pragma unroll
  for (int mi=0;mi<4;mi++){
    int row0 = m0 + wm*64 + mi*16 + hi*4;
    #pragma unroll
    for (int ni=0;ni<NF;ni++){
      int col = n0 + wn*WNW + ni*16 + ln;
      float bc = bias[col];
      #pragma unroll
      for (int r=0;r<4;r++){
        float v = acc[mi][ni][r] + bc;
        if (EPI == 2) v = fmaxf(v, 0.f);
        if (EPI == 0) ((float*)C)[(size_t)(row0+r)*ldo + col] = v;
        else          ((u16*) C)[(size_t)(row0+r)*ldo + col] = f2b(v);
      }
    }
  }
}

// ---------------- flash attention, swapped QK^T, in-register softmax ----------------
__global__ __launch_bounds__(256) void attn_kernel(const u16* __restrict__ qkv,
                                                   const u16* __restrict__ vt,
                                                   u16* __restrict__ ctx){
  __shared__ u16 Ks[2][64*64];
  __shared__ u16 Vs[2][64*64];
  int tid = threadIdx.x, l = tid & 63, w = tid >> 6;
  int hi = l >> 4, ln = l & 15;
  int orig = ((blockIdx.x & 7) << 7) | (blockIdx.x >> 3);   // XCD-contiguous (b)
  int qt = orig & 15, h = (orig >> 4) & 7, b = orig >> 7;
  size_t rowbase = (size_t)b * S_;

  // Q as B-operand fragments (n = q = ln), held for whole kernel
  int qrow = qt*64 + w*16 + ln;
  s16x8 bq[2];
  #pragma unroll
  for (int s = 0; s < 2; s++)
    bq[s] = *(const s16x8*)&qkv[(rowbase + qrow)*1536 + h*64 + s*32 + hi*8];

  int rl = l >> 3;
  int cg = (l & 7) ^ rl;            // pre-swizzled global 16B-chunk index
  const u16* kb = qkv + rowbase*1536 + 512 + h*64 + cg*8;
  const u16* vb = vt + (size_t)((b*8 + h)*64)*1024 + cg*8;

  f32x4 o[4];
  #pragma unroll
  for (int i = 0; i < 4; i++) o[i] = (f32x4){0.f,0.f,0.f,0.f};
  float m_ = -1e30f, l_ = 0.f;

  #define STAGE(buf, kt) do { \
    _Pragma("unroll") \
    for (int r2 = 0; r2 < 2; r2++){ \
      int rr = r2*32 + w*8; \
      gload16(kb + (size_t)((kt)*64 + rr + rl)*1536, &Ks[buf][rr*64]); \
      gload16(vb + (size_t)(rr + rl)*1024 + (kt)*64, &Vs[buf][rr*64]); \
    } } while(0)

  STAGE(0, 0);
  STAGE(1, 1);
  asm volatile("s_waitcnt vmcnt(4)" ::: "memory");   // tile 0 staged
  __builtin_amdgcn_s_barrier();
  __builtin_amdgcn_sched_barrier(0);

  for (int kt = 0; kt < 16; kt++){
    int cur = kt & 1;
    // ---- read all fragments of cur into registers ----
    s16x8 ak[4][2], av[4][2];
    #pragma unroll
    for (int nf = 0; nf < 4; nf++){
      int n = nf*16 + ln;
      int swz = n & 7;
      #pragma unroll
      for (int s = 0; s < 2; s++){
        ak[nf][s] = *(const s16x8*)&Ks[cur][n*64 + (((s*4 + hi) ^ swz)*8)];
        av[nf][s] = *(const s16x8*)&Vs[cur][n*64 + (((s*4 + hi) ^ swz)*8)];
      }
    }
    asm volatile("s_waitcnt lgkmcnt(0)" ::: "memory");
    __builtin_amdgcn_sched_barrier(0);
    __builtin_amdgcn_s_barrier();          // all waves done READING cur
    __builtin_amdgcn_sched_barrier(0);
    if (kt < 14) STAGE(cur, kt+2);         // overwrite cur with tile kt+2

    // ---- S^T = K Q^T : sacc[nf][r] = S[k=nf*16+hi*4+r][q=ln] (unscaled) ----
    f32x4 sacc[4];
    __builtin_amdgcn_s_setprio(1);
    #pragma unroll
    for (int nf = 0; nf < 4; nf++){
      f32x4 acc = (f32x4){0.f,0.f,0.f,0.f};
      #pragma unroll
      for (int s = 0; s < 2; s++)
        acc = __builtin_amdgcn_mfma_f32_16x16x32_bf16(ak[nf][s], bq[s], acc, 0,0,0);
      sacc[nf] = acc;
    }
    __builtin_amdgcn_s_setprio(0);

    // ---- in-register online softmax (per-lane q = ln) ----
    float mx = sacc[0][0];
    #pragma unroll
    for (int nf = 0; nf < 4; nf++)
      #pragma unroll
      for (int r = 0; r < 4; r++) mx = fmaxf(mx, sacc[nf][r]);
    mx = fmaxf(mx, __shfl_xor(mx, 16, 64));
    mx = fmaxf(mx, __shfl_xor(mx, 32, 64));
    float mnew  = fmaxf(m_, mx * 0.125f);
    float alpha = __expf(m_ - mnew);
    float p[4][4];
    float rs = 0.f;
    #pragma unroll
    for (int nf = 0; nf < 4; nf++)
      #pragma unroll
      for (int r = 0; r < 4; r++){
        p[nf][r] = __expf(fmaf(sacc[nf][r], 0.125f, -mnew));
        rs += p[nf][r];
      }
    rs += __shfl_xor(rs, 16, 64);
    rs += __shfl_xor(rs, 32, 64);
    l_ = l_*alpha + rs;
    m_ = mnew;
    #pragma unroll
    for (int df = 0; df < 4; df++) o[df] *= alpha;

    // ---- pack P to bf16 pairs: W0/W1[nf] cover k = nf*16+hi*4+{0,1}/{2,3} ----
    unsigned W0[4], W1[4];
    #pragma unroll
    for (int nf = 0; nf < 4; nf++){
      W0[nf] = cvtpk(p[nf][0], p[nf][1]);
      W1[nf] = cvtpk(p[nf][2], p[nf][3]);
    }

    // ---- redistribute to PV B-fragments (16 shfl + selects) ----
    unsigned bw[2][4];
    {
      int base = (hi & 1) * 32 + ln;
      bool sel = (hi < 2);
      #pragma unroll
      for (int pat = 0; pat < 2; pat++){
        int src = base + pat*16;
        unsigned a0 = __shfl((int)W0[0], src, 64);
        unsigned a1 = __shfl((int)W0[1], src, 64);
        unsigned a2 = __shfl((int)W0[2], src, 64);
        unsigned a3 = __shfl((int)W0[3], src, 64);
        unsigned c0 = __shfl((int)W1[0], src, 64);
        unsigned c1 = __shfl((int)W1[1], src, 64);
        unsigned c2 = __shfl((int)W1[2], src, 64);
        unsigned c3 = __shfl((int)W1[3], src, 64);
        bw[0][pat*2+0] = sel ? a0 : a1;
        bw[0][pat*2+1] = sel ? c0 : c1;
        bw[1][pat*2+0] = sel ? a2 : a3;
        bw[1][pat*2+1] = sel ? c2 : c3;
      }
    }

    // ---- O^T += V^T P : o[df][r] = O[d=df*16+hi*4+r][q=ln] ----
    __builtin_amdgcn_s_setprio(1);
    #pragma unroll
    for (int s = 0; s < 2; s++){
      union { unsigned u[4]; s16x8 v; } bp;
      bp.u[0] = bw[s][0]; bp.u[1] = bw[s][1];
      bp.u[2] = bw[s][2]; bp.u[3] = bw[s][3];
      #pragma unroll
      for (int df = 0; df < 4; df++)
        o[df] = __builtin_amdgcn_mfma_f32_16x16x32_bf16(av[df][s], bp.v, o[df], 0,0,0);
    }
    __builtin_amdgcn_s_setprio(0);

    // ---- next-buffer staging complete before its reads ----
    if (kt < 15){
      if (kt < 14) asm volatile("s_waitcnt vmcnt(4)" ::: "memory");
      else         asm volatile("s_waitcnt vmcnt(0)" ::: "memory");
      __builtin_amdgcn_s_barrier();
      __builtin_amdgcn_sched_barrier(0);
    }
  }
  #undef STAGE

  // ---- coalesced ctx write via per-wave LDS bounce ----
  __builtin_amdgcn_s_barrier();            // all waves done with K/V LDS
  float inv = 1.f / l_;
  u16* ob = ((u16*)Ks) + w*1152;           // [16 q][72 d] per wave
  #pragma unroll
  for (int df = 0; df < 4; df++){
    unsigned w0 = cvtpk(o[df][0]*inv, o[df][1]*inv);
    unsigned w1 = cvtpk(o[df][2]*inv, o[df][3]*inv);
    *(unsigned*)&ob[ln*72 + df*16 + hi*4]     = w0;
    *(unsigned*)&ob[ln*72 + df*16 + hi*4 + 2] = w1;
  }
  asm volatile("s_waitcnt lgkmcnt(0)" ::: "memory");
  __builtin_amdgcn_sched_barrier(0);
  int r2 = l >> 2, c2 = (l & 3) * 16;
  uint4 q0 = *(uint4*)&ob[r2*72 + c2];
  uint4 q1 = *(uint4*)&ob[r2*72 + c2 + 8];
  size_t row = rowbase + qt*64 + w*16 + r2;
  *(uint4*)&ctx[row*512 + h*64 + c2]     = q0;
  *(uint4*)&ctx[row*512 + h*64 + c2 + 8] = q1;
}

// ---------------- LN1: out1b = bf16(LN(st + tmp)) ----------------
__global__ __launch_bounds__(64) void ln1_kernel(
    const float* __restrict__ tmp, const float* __restrict__ st,
    const float* __restrict__ g, const float* __restrict__ bt,
    u16* __restrict__ out1b){
  int row = blockIdx.x, lane = threadIdx.x;
  size_t base = (size_t)row*512 + lane*8;
  float v[8];
  {
    const float4* tp = (const float4*)(tmp + base);
    const float4* sp = (const float4*)(st + base);
    float4 t0=tp[0], t1=tp[1], s0=sp[0], s1=sp[1];
    v[0]=t0.x+s0.x; v[1]=t0.y+s0.y; v[2]=t0.z+s0.z; v[3]=t0.w+s0.w;
    v[4]=t1.x+s1.x; v[5]=t1.y+s1.y; v[6]=t1.z+s1.z; v[7]=t1.w+s1.w;
  }
  float sum=0.f, sq=0.f;
  #pragma unroll
  for (int j=0;j<8;j++){ sum += v[j]; sq += v[j]*v[j]; }
  sum = wred_sum(sum); sq = wred_sum(sq);
  float mean = sum*(1.f/512.f);
  float var  = sq*(1.f/512.f) - mean*mean;
  float rstd = rsqrtf(fmaxf(var, 0.f) + 1e-6f);
  int c0 = lane*8;
  u16x8 ob;
  #pragma unroll
  for (int j=0;j<8;j++) ob[j] = f2b((v[j]-mean)*rstd*g[c0+j] + bt[c0+j]);
  *(u16x8*)(out1b + base) = ob;
}

// ---------------- LNf: in-place LN over DFF=2048 ----------------
__global__ __launch_bounds__(256) void lnf_kernel(
    u16* __restrict__ hbuf, const float* __restrict__ g, const float* __restrict__ bt){
  int row = blockIdx.x, tid = threadIdx.x, lane = tid & 63, wv = tid >> 6;
  size_t base = (size_t)row*2048 + tid*8;
  u16x8 x8 = *(const u16x8*)&hbuf[base];
  float v[8];
  #pragma unroll
  for (int j=0;j<8;j++) v[j] = b2f(x8[j]);
  float sum=0.f, sq=0.f;
  #pragma unroll
  for (int j=0;j<8;j++){ sum += v[j]; sq += v[j]*v[j]; }
  sum = wred_sum(sum); sq = wred_sum(sq);
  __shared__ float rs[8];
  if (lane == 0){ rs[wv] = sum; rs[4+wv] = sq; }
  __syncthreads();
  sum = rs[0]+rs[1]+rs[2]+rs[3];
  sq  = rs[4]+rs[5]+rs[6]+rs[7];
  float mean = sum*(1.f/2048.f);
  float var  = sq*(1.f/2048.f) - mean*mean;
  float rstd = rsqrtf(fmaxf(var, 0.f) + 1e-6f);
  int c0 = tid*8;
  u16x8 o;
  #pragma unroll
  for (int j=0;j<8;j++) o[j] = f2b((v[j]-mean)*rstd*g[c0+j] + bt[c0+j]);
  *(u16x8*)&hbuf[base] = o;
}

// ---------------- LN2 + ACT mix + next-step ponder dot (bf16 residual) ----------------
__global__ __launch_bounds__(64) void ln2mix_kernel(
    const float* __restrict__ tmp, const u16* __restrict__ out1b,
    const float* __restrict__ g, const float* __restrict__ bt,
    const float* __restrict__ uw, const float* __restrict__ aw,
    float* __restrict__ st, u16* __restrict__ stb, float* __restrict__ dotb){
  int row = blockIdx.x, lane = threadIdx.x;
  size_t base = (size_t)row*512 + lane*8;
  float v[8], sv[8];
  {
    const float4* tp = (const float4*)(tmp  + base);
    const float4* sp = (const float4*)(st   + base);
    u16x8 o8 = *(const u16x8*)(out1b + base);
    float4 t0=tp[0], t1=tp[1], s0=sp[0], s1=sp[1];
    v[0]=t0.x+b2f(o8[0]); v[1]=t0.y+b2f(o8[1]); v[2]=t0.z+b2f(o8[2]); v[3]=t0.w+b2f(o8[3]);
    v[4]=t1.x+b2f(o8[4]); v[5]=t1.y+b2f(o8[5]); v[6]=t1.z+b2f(o8[6]); v[7]=t1.w+b2f(o8[7]);
    sv[0]=s0.x; sv[1]=s0.y; sv[2]=s0.z; sv[3]=s0.w;
    sv[4]=s1.x; sv[5]=s1.y; sv[6]=s1.z; sv[7]=s1.w;
  }
  float sum=0.f, sq=0.f;
  #pragma unroll
  for (int j=0;j<8;j++){ sum += v[j]; sq += v[j]*v[j]; }
  sum = wred_sum(sum); sq = wred_sum(sq);
  float mean = sum*(1.f/512.f);
  float var  = sq*(1.f/512.f) - mean*mean;
  float rstd = rsqrtf(fmaxf(var, 0.f) + 1e-6f);
  float u = uw[row], um1 = 1.f - u;
  int c0 = lane*8;
  float z[8]; u16x8 ob;
  #pragma unroll
  for (int j=0;j<8;j++){
    float y = (v[j]-mean)*rstd*g[c0+j] + bt[c0+j];
    z[j] = y*u + sv[j]*um1;
    ob[j] = f2b(z[j]);
  }
  float4* op = (float4*)(st + base);
  op[0] = make_float4(z[0],z[1],z[2],z[3]);
  op[1] = make_float4(z[4],z[5],z[6],z[7]);
  *(u16x8*)(stb + base) = ob;
  const float4* wp = (const float4*)aw + (size_t)lane*2;
  float4 w0 = wp[0], w1 = wp[1];
  float d = z[0]*w0.x + z[1]*w0.y + z[2]*w0.z + z[3]*w0.w
          + z[4]*w1.x + z[5]*w1.y + z[6]*w1.z + z[7]*w1.w;
  d = wred_sum(d);
  if (lane == 0) dotb[row] = d;
}

// ---------------- ACT halting from precomputed dot ----------------
__global__ __launch_bounds__(256) void act_kernel(
    const float* __restrict__ dotb, const float* __restrict__ ab,
    float* __restrict__ hp, float* __restrict__ rem, float* __restrict__ uw){
  int tok = blockIdx.x*256 + threadIdx.x;
  float t = dotb[tok] + ab[0];
  float p = 1.f / (1.f + expf(-t));
  float h = hp[tok], r = rem[tok];
  float still = (h < 1.f) ? 1.f : 0.f;
  float cand  = h + p*still;
  float nh  = (cand > 0.99f)  ? still : 0.f;
  float st2 = (cand <= 0.99f) ? still : 0.f;
  h += p*st2;
  r += nh*(1.f - h);
  h += nh*r;
  hp[tok] = h; rem[tok] = r;
  uw[tok] = p*st2 + nh*r;
}

// ---------------- host launch ----------------
extern "C" void kernel_launch(void* const* d_in, const int* in_sizes, int n_in,
                              void* d_out, int out_size, void* d_ws, size_t ws_size,
                              hipStream_t stream){
  const float* x     = (const float*)d_in[0];
  const float* wq    = (const float*)d_in[1];
  const float* bq    = (const float*)d_in[2];
  const float* wk    = (const float*)d_in[3];
  const float* bk    = (const float*)d_in[4];
  const float* wv    = (const float*)d_in[5];
  const float* bv    = (const float*)d_in[6];
  const float* wo    = (const float*)d_in[7];
  const float* bo    = (const float*)d_in[8];
  const float* w1    = (const float*)d_in[9];
  const float* b1    = (const float*)d_in[10];
  const float* lnf_g = (const float*)d_in[11];
  const float* lnf_b = (const float*)d_in[12];
  const float* w2    = (const float*)d_in[13];
  const float* b2    = (const float*)d_in[14];
  const float* ln1_g = (const float*)d_in[15];
  const float* ln1_b = (const float*)d_in[16];
  const float* ln2_g = (const float*)d_in[17];
  const float* ln2_b = (const float*)d_in[18];
  const float* aw    = (const float*)d_in[19];
  const float* ab    = (const float*)d_in[20];
  float* st = (float*)d_out;

  char* cur = (char*)d_ws;
  auto alloc = [&](size_t n){ void* p = cur; cur += (n + 255) & ~(size_t)255; return p; };
  u16*  wqkv_t = (u16*)alloc((size_t)1536*512*2);
  u16*  wo_t   = (u16*)alloc((size_t)512*512*2);
  u16*  w1_t   = (u16*)alloc((size_t)2048*512*2);
  u16*  w2_t   = (u16*)alloc((size_t)512*2048*2);
  float* bqkv  = (float*)alloc(1536*4);
  u16*  stb    = (u16*)alloc((size_t)M_*512*2);
  u16*  qkv    = (u16*)alloc((size_t)M_*1536*2);
  u16*  ctx    = (u16*)alloc((size_t)M_*512*2);
  u16*  out1b  = (u16*)alloc((size_t)M_*512*2);
  u16*  hbuf   = (u16*)alloc((size_t)M_*2048*2);
  float* tmp   = (float*)alloc((size_t)M_*512*4);
  float* halt  = (float*)alloc((size_t)3*M_*4);
  float* dotb  = (float*)alloc((size_t)M_*4);
  float* hp = halt, *rem = halt + M_, *uw = halt + 2*M_;
  u16* vt = hbuf;   // vt lifetime (qkv->attn) disjoint from hbuf (ffn1->ffn2)

  prep_kernel<<<2048, 256, 0, stream>>>(x, aw, st, stb, dotb);
  zero_kernel<<<96, 256, 0, stream>>>(halt);
  packb_kernel<<<6, 256, 0, stream>>>(bq, bk, bv, bqkv);
  tcast_kernel<<<64,  256, 0, stream>>>(wq, wqkv_t,            512, 512);
  tcast_kernel<<<64,  256, 0, stream>>>(wk, wqkv_t + 512*512,  512, 512);
  tcast_kernel<<<64,  256, 0, stream>>>(wv, wqkv_t + 1024*512, 512, 512);
  tcast_kernel<<<64,  256, 0, stream>>>(wo, wo_t, 512, 512);
  tcast_kernel<<<256, 256, 0, stream>>>(w1, w1_t, 512, 2048);
  tcast_kernel<<<256, 256, 0, stream>>>(w2, w2_t, 2048, 512);

  for (int s = 0; s < STEPS_; s++){
    act_kernel<<<M_/256, 256, 0, stream>>>(dotb, ab, hp, rem, uw);
    gemm_kernel<1,128><<<64*12, 256, 0, stream>>>(stb,   wqkv_t, bqkv, qkv,  12, 512,  1536, vt);
    attn_kernel<<<1024, 256, 0, stream>>>(qkv, vt, ctx);
    gemm_kernel<0,64><<<128*4, 256, 0, stream>>>(ctx,   wo_t,   bo,   tmp,  4,  512,  512, nullptr);
    ln1_kernel<<<M_, 64, 0, stream>>>(tmp, st, ln1_g, ln1_b, out1b);
    gemm_kernel<2,128><<<64*16, 256, 0, stream>>>(out1b, w1_t,   b1,   hbuf, 16, 512,  2048, nullptr);
    lnf_kernel<<<M_, 256, 0, stream>>>(hbuf, lnf_g, lnf_b);
    gemm_kernel<0,64><<<128*4, 256, 0, stream>>>(hbuf,  w2_t,   b2,   tmp,  4,  2048, 512, nullptr);
    ln2mix_kernel<<<M_, 64, 0, stream>>>(tmp, out1b, ln2_g, ln2_b, uw, aw, st, stb, dotb);
  }
}